// Round 8
// baseline (1029.493 us; speedup 1.0000x reference)
//
#include <hip/hip_runtime.h>
#include <math.h>

#define Bb   4
#define Nn   4096
#define Mm   4096
#define Dd   256
#define D0c  128
#define Kc   64

typedef _Float16 half8 __attribute__((ext_vector_type(8)));
typedef float    f32x4 __attribute__((ext_vector_type(4)));

__device__ __forceinline__ unsigned encf(float f) {
    unsigned u = __float_as_uint(f);
    return (u & 0x80000000u) ? ~u : (u | 0x80000000u);
}
__device__ __forceinline__ float decf(unsigned u) {
    return (u & 0x80000000u) ? __uint_as_float(u ^ 0x80000000u) : __uint_as_float(~u);
}
__device__ __forceinline__ float softplusf(float x) {
    return fmaxf(x, 0.f) + log1pf(expf(-fabsf(x)));
}
__device__ __forceinline__ void gl_lds16(const _Float16* g, _Float16* l) {
    __builtin_amdgcn_global_load_lds((const __attribute__((address_space(1))) void*)g,
                                     (__attribute__((address_space(3))) void*)l, 16, 0, 0);
}

// Block->tile decode for 256x128 tiles: grid = 32 mt x 16 nt per batch (512 blocks).
// swz=2: CB==2 (1024 blocks) XCD-chunked: xcd owns an 8mt x 8nt super-tile
// (panels: 8x128 B-cols = 1 MB + 8x256 A-rows = 2 MB -> 3 MB < 4 MB XCD L2).
// swz=1: CB==1 (512 blocks). swz=0: plain linear (fallback).
__device__ __forceinline__ void decode_tile(int bid, int swz, int& mt, int& nt, int& zz) {
    if (swz == 2) {
        const int xcd = bid & 7, k = bid >> 3;   // k in 0..127
        zz = k >> 6;
        const int kk = k & 63;
        mt = (xcd & 3) * 8 + (kk & 7);
        nt = (xcd >> 2) * 8 + (kk >> 3);
    } else if (swz == 1) {
        const int xcd = bid & 7, k = bid >> 3;   // k in 0..63
        zz = 0;
        mt = (xcd & 3) * 8 + (k & 7);
        nt = (xcd >> 2) * 8 + (k >> 3);
    } else {
        mt = bid & 31; nt = (bid >> 5) & 15; zz = bid >> 9;
    }
}

// ---------------- prep: normalize rows, split fp16 hi/lo, tiled layout -------------
// lo part stored UNSCALED (x - h): correction MFMAs accumulate into the same fp32
// accumulator as h*h. Also zero-inits the persistent per-batch column-max buffer.
__global__ __launch_bounds__(256) void prep_kernel(
    const float* __restrict__ dA, const float* __restrict__ dB,
    _Float16* __restrict__ Ah, _Float16* __restrict__ Al,
    _Float16* __restrict__ Bh, _Float16* __restrict__ Bl,
    unsigned* __restrict__ colMaxU)
{
    const int t = threadIdx.x, wave = t >> 6, lane = t & 63;
    const int row = blockIdx.x * 4 + wave;           // 0..16383
    if (blockIdx.y == 0 && lane == 0) colMaxU[row] = 0u;
    const float* src = blockIdx.y ? dB : dA;
    _Float16* dh = blockIdx.y ? Bh : Ah;
    _Float16* dl = blockIdx.y ? Bl : Al;
    const float4 v = *(const float4*)&src[(size_t)row * Dd + lane * 4];
    float ss = v.x * v.x + v.y * v.y + v.z * v.z + v.w * v.w;
#pragma unroll
    for (int m = 32; m; m >>= 1) ss += __shfl_xor(ss, m, 64);
    const float inv = 1.0f / sqrtf(ss);
    float x[4] = {v.x * inv, v.y * inv, v.z * inv, v.w * inv};
    union { _Float16 h[4]; uint2 u; } ph, pl;
#pragma unroll
    for (int i = 0; i < 4; i++) {
        _Float16 h = (_Float16)x[i];
        ph.h[i] = h;
        pl.h[i] = (_Float16)(x[i] - (float)h);    // unscaled residual
    }
    const size_t toff = (size_t)(row >> 7) * 32768
                      + (size_t)(lane >> 3) * 4096
                      + (size_t)((lane >> 1) & 3) * 1024
                      + (size_t)(row & 127) * 8 + (lane & 1) * 4;
    *(uint2*)&dh[toff] = ph.u;
    *(uint2*)&dl[toff] = pl.u;
}

// ---------------- MFMA sim kernel: 256x128 tile, 8 waves (4x2 grid of 64x64) -------
// 16x16x32 MFMA (r7's 32x32 regressed: NT-store write amplification). Staging LDS
// 48 KB/k-step (Ah 16K | Al 16K | Bh 8K | Bl 8K), epilogue buffers ALIAS the staging
// region -> 48 KB/block -> 3 blocks/CU = 24 waves/CU for cross-block phase overlap.
// A layout per array: [quad][grp2][128][8] halfs; B: [quad][128][8].
// PB=0: row/col exp-sum partials + optional NT STORE. PB=1: argmax (fallback only).
template<int PB, int STORE>
__global__ __launch_bounds__(512, 6) void sim_kernel(
    const _Float16* __restrict__ Ah, const _Float16* __restrict__ Al,
    const _Float16* __restrict__ Bh, const _Float16* __restrict__ Bl,
    const float* __restrict__ Lrow_g, const float* __restrict__ Lcol_g,
    float* __restrict__ rowsumP, float* __restrict__ colsumP,
    float* __restrict__ rkey, int* __restrict__ rmArr, float* __restrict__ rcvArr,
    unsigned* __restrict__ cmU, float* __restrict__ simG, int b0, int swz)
{
    __shared__ _Float16 S[24576];               // 48 KB staging (+aliased epilogue)

    const int t = threadIdx.x;
    const int wave = t >> 6, lane = t & 63;
    const int wr = wave >> 1, wc = wave & 1;    // 4x2 wave grid, 64x64 each
    const int quad = lane >> 4, l15 = lane & 15;
    int mt, nt, bbl;
    decode_tile(blockIdx.x, swz, mt, nt, bbl);
    const int bb = b0 + bbl;
    const int n0 = nt * 256, m0 = mt * 128;

    const _Float16* gAh = Ah + (size_t)(bb * 32 + nt * 2) * 32768;
    const _Float16* gAl = Al + (size_t)(bb * 32 + nt * 2) * 32768;
    const _Float16* gBh = Bh + (size_t)(bb * 32 + mt) * 32768;
    const _Float16* gBl = Bl + (size_t)(bb * 32 + mt) * 32768;

    f32x4 acc[4][4];                            // [ti][tj]
#pragma unroll
    for (int ti = 0; ti < 4; ti++)
#pragma unroll
        for (int tj = 0; tj < 4; tj++) acc[ti][tj] = (f32x4)0.f;

    const int grpA = wr >> 1;                   // A group (rows 0-127 / 128-255)
    const int arl = (wr & 1) * 64;              // row base within group

    for (int kc8 = 0; kc8 < 8; ++kc8) {
        // stage 48 chunks of 1 KB; wave w stages chunks w*6 .. w*6+5
#pragma unroll
        for (int q = 0; q < 6; ++q) {
            const int c = wave * 6 + q;
            _Float16* dst = S + c * 512;
            const _Float16* src;
            if (c < 32) {                       // A arrays: 16 chunks each
                const int ca = c & 15;          // [quad=ca>>2][grp=(ca>>1)&1][rh=ca&1]
                const _Float16* gA = (c < 16) ? gAh : gAl;
                src = gA + ((ca >> 1) & 1) * 32768 + kc8 * 4096
                        + (ca >> 2) * 1024 + (ca & 1) * 512;
            } else {                            // B arrays: 8 chunks each
                const int cb = c & 7;           // [quad=cb>>1][rh=cb&1]
                const _Float16* gB = (c < 40) ? gBh : gBl;
                src = gB + kc8 * 4096 + (cb >> 1) * 1024 + (cb & 1) * 512;
            }
            gl_lds16(src + lane * 8, dst);
        }
        __syncthreads();

        half8 afh[4], afl[4];
#pragma unroll
        for (int ti = 0; ti < 4; ++ti) {
            const int r8 = (arl + ti * 16 + l15) * 8;
            afh[ti] = *(const half8*)&S[        quad * 2048 + grpA * 1024 + r8];
            afl[ti] = *(const half8*)&S[8192 + quad * 2048 + grpA * 1024 + r8];
        }
#pragma unroll
        for (int tj = 0; tj < 4; ++tj) {
            const int c8 = (wc * 64 + tj * 16 + l15) * 8;
            half8 bh = *(const half8*)&S[16384 + quad * 1024 + c8];
            half8 bl = *(const half8*)&S[20480 + quad * 1024 + c8];
#pragma unroll
            for (int ti = 0; ti < 4; ++ti) {
                acc[ti][tj] = __builtin_amdgcn_mfma_f32_16x16x32_f16(afh[ti], bh, acc[ti][tj], 0, 0, 0);
                acc[ti][tj] = __builtin_amdgcn_mfma_f32_16x16x32_f16(afh[ti], bl, acc[ti][tj], 0, 0, 0);
                acc[ti][tj] = __builtin_amdgcn_mfma_f32_16x16x32_f16(afl[ti], bh, acc[ti][tj], 0, 0, 0);
            }
        }
        __syncthreads();
    }

    if (!PB) {
        float* rowpS = (float*)S;               // 256 (aliases dead staging)
        float* colpS = (float*)S + 256;         // 128
        if (t < 256) rowpS[t] = 0.f;
        if (t < 128) colpS[t] = 0.f;
        __syncthreads();

        float rp[16], cp[4] = {0.f, 0.f, 0.f, 0.f};
#pragma unroll
        for (int i = 0; i < 16; ++i) rp[i] = 0.f;
#pragma unroll
        for (int ti = 0; ti < 4; ++ti)
#pragma unroll
            for (int tj = 0; tj < 4; ++tj)
#pragma unroll
                for (int r = 0; r < 4; ++r) {
                    float e = __expf(fmaf(20.f, acc[ti][tj][r], -20.f));
                    rp[ti * 4 + r] += e;
                    cp[tj] += e;
                }
#pragma unroll
        for (int i = 0; i < 16; ++i)
#pragma unroll
            for (int m = 1; m < 16; m <<= 1) rp[i] += __shfl_xor(rp[i], m, 64);
        if (l15 == 0) {
#pragma unroll
            for (int ti = 0; ti < 4; ++ti)
#pragma unroll
                for (int r = 0; r < 4; ++r)
                    atomicAdd(&rowpS[wr * 64 + ti * 16 + quad * 4 + r], rp[ti * 4 + r]);
        }
#pragma unroll
        for (int tj = 0; tj < 4; ++tj) {
            cp[tj] += __shfl_xor(cp[tj], 16, 64);
            cp[tj] += __shfl_xor(cp[tj], 32, 64);
        }
        if (quad == 0) {
#pragma unroll
            for (int tj = 0; tj < 4; ++tj) atomicAdd(&colpS[wc * 64 + tj * 16 + l15], cp[tj]);
        }
        __syncthreads();
        if (t < 256) rowsumP[(size_t)(bb * 32 + mt) * Nn + n0 + t] = rowpS[t];
        if (t < 128) colsumP[(size_t)(bb * 16 + nt) * Mm + m0 + t] = colpS[t];
        if (STORE) {
            // nontemporal: stream to HBM, keep L2 clean for the staged panels
            float* base = simG + ((size_t)bbl * Nn + n0) * Mm + m0 + wc * 64;
#pragma unroll
            for (int ti = 0; ti < 4; ++ti)
#pragma unroll
                for (int r = 0; r < 4; ++r) {
                    float* rowp_ = base + (size_t)(wr * 64 + ti * 16 + quad * 4 + r) * Mm;
#pragma unroll
                    for (int tj = 0; tj < 4; ++tj)
                        __builtin_nontemporal_store(acc[ti][tj][r], rowp_ + tj * 16 + l15);
                }
        }
    } else {
        float*    shL  = (float*)S;                    // 256
        float*    shLc = (float*)S + 256;              // 128
        float*    s_bk = (float*)S + 384;              // 256
        float*    s_bc = (float*)S + 640;              // 256
        int*      s_bm = (int*)((float*)S + 896);      // 256
        unsigned* colu = (unsigned*)((float*)S + 1152);// 128
        if (t < 256) shL[t] = Lrow_g[bb * Nn + n0 + t];
        if (t < 128) { shLc[t] = Lcol_g[bb * Mm + m0 + t]; colu[t] = 0u; }
        __syncthreads();

        float Lr[16];
#pragma unroll
        for (int ti = 0; ti < 4; ++ti)
#pragma unroll
            for (int r = 0; r < 4; ++r)
                Lr[ti * 4 + r] = shL[wr * 64 + ti * 16 + quad * 4 + r];

        float bk[16], bc[16];
        int bm[16];
        unsigned cu[4];
#pragma unroll
        for (int i = 0; i < 16; i++) { bk[i] = -INFINITY; bc[i] = -INFINITY; bm[i] = 0x7fffffff; }
#pragma unroll
        for (int j = 0; j < 4; j++) cu[j] = 0u;

#pragma unroll
        for (int ti = 0; ti < 4; ++ti)
#pragma unroll
            for (int tj = 0; tj < 4; ++tj)
#pragma unroll
                for (int r = 0; r < 4; ++r) {
                    float cv = fmaf(40.f, acc[ti][tj][r], -40.f - Lr[ti * 4 + r]);
                    float kv = cv - shLc[wc * 64 + tj * 16 + l15];
                    const int i = ti * 4 + r;
                    if (kv > bk[i]) { bk[i] = kv; bm[i] = m0 + wc * 64 + tj * 16 + l15; bc[i] = cv; }
                    unsigned e = encf(cv);
                    if (e > cu[tj]) cu[tj] = e;
                }
#pragma unroll
        for (int i = 0; i < 16; ++i) {
#pragma unroll
            for (int m = 1; m < 16; m <<= 1) {
                float okv = __shfl_xor(bk[i], m, 64);
                int   om  = __shfl_xor(bm[i], m, 64);
                float ocv = __shfl_xor(bc[i], m, 64);
                if (okv > bk[i] || (okv == bk[i] && om < bm[i])) { bk[i] = okv; bm[i] = om; bc[i] = ocv; }
            }
        }
        if (l15 == 0 && wc == 0) {
#pragma unroll
            for (int ti = 0; ti < 4; ++ti)
#pragma unroll
                for (int r = 0; r < 4; ++r) {
                    const int row = wr * 64 + ti * 16 + quad * 4 + r, i = ti * 4 + r;
                    s_bk[row] = bk[i]; s_bm[row] = bm[i]; s_bc[row] = bc[i];
                }
        }
#pragma unroll
        for (int tj = 0; tj < 4; ++tj) {
            unsigned o = __shfl_xor(cu[tj], 16, 64); if (o > cu[tj]) cu[tj] = o;
            o = __shfl_xor(cu[tj], 32, 64); if (o > cu[tj]) cu[tj] = o;
        }
        if (quad == 0) {
#pragma unroll
            for (int tj = 0; tj < 4; ++tj) atomicMax(&colu[wc * 64 + tj * 16 + l15], cu[tj]);
        }
        __syncthreads();
        if (l15 == 0 && wc == 1) {
#pragma unroll
            for (int ti = 0; ti < 4; ++ti)
#pragma unroll
                for (int r = 0; r < 4; ++r) {
                    const int row = wr * 64 + ti * 16 + quad * 4 + r, i = ti * 4 + r;
                    float k0 = s_bk[row];
                    if (bk[i] > k0 || (bk[i] == k0 && bm[i] < s_bm[row])) {
                        s_bk[row] = bk[i]; s_bm[row] = bm[i]; s_bc[row] = bc[i];
                    }
                }
        }
        __syncthreads();
        if (t < 256) {
            size_t idx = (size_t)(bb * 32 + mt) * Nn + n0 + t;
            rkey[idx] = s_bk[t]; rmArr[idx] = s_bm[t]; rcvArr[idx] = s_bc[t];
        }
        if (t < 128) cmU[(size_t)(bb * 16 + nt) * Mm + m0 + t] = colu[t];
    }
}

// ---------------- reduce partials -> L = log(rowsum), Lc = log(colsum), chunked -----
// rows: 32 mt-partials; cols: 16 nt-partials (256-row tiles).
__global__ __launch_bounds__(256) void logsum_kernel(
    const float* __restrict__ rowsumP, const float* __restrict__ colsumP,
    float* __restrict__ Lrow, float* __restrict__ Lcol, int b0, int CB)
{
    int t = blockIdx.x * 256 + threadIdx.x;
    int half = CB * 4096;
    int which = t >= half;
    int idx = which ? (t - half) : t;
    int bb = b0 + (idx >> 12), n = idx & 4095;
    float s = 0.f;
    if (which) {
        for (int nt = 0; nt < 16; ++nt) s += colsumP[(size_t)(bb * 16 + nt) * 4096 + n];
        Lcol[bb * 4096 + n] = logf(s);
    } else {
        for (int mt = 0; mt < 32; ++mt) s += rowsumP[(size_t)(bb * 32 + mt) * 4096 + n];
        Lrow[bb * 4096 + n] = logf(s);
    }
}

// ---------------- scan: block = 16 rows x 1024 cols (quarter), NT loads ------------
// Column-max goes straight to the persistent per-batch colMaxU via global atomicMax.
__global__ __launch_bounds__(256) void scan_kernel(
    const float* __restrict__ simG,
    const float* __restrict__ Lrow, const float* __restrict__ Lcol,
    float* __restrict__ kvP, float* __restrict__ cvP, int* __restrict__ jP,
    unsigned* __restrict__ colMaxU, int b0)
{
    __shared__ unsigned colu[1024];          // 4 KB
    const int t = threadIdx.x, wave = t >> 6, lane = t & 63;
    const int blk = blockIdx.x;              // 0 .. CB*1024-1
    const int bbl = blk >> 10;
    const int r10 = blk & 1023;
    const int stripe = r10 >> 2, q = r10 & 3;   // 256 stripes of 16 rows; col quarter
    const int bb = b0 + bbl;
    const int col0 = q * 1024;
    const int row0 = stripe * 16 + wave * 4;

    for (int i = t; i < 1024; i += 256) colu[i] = 0u;
    __syncthreads();

    f32x4 Lc4[4], cmax[4];
    const float* LcB = Lcol + bb * Mm + col0;
#pragma unroll
    for (int c = 0; c < 4; ++c) {
        Lc4[c] = *(const f32x4*)&LcB[c * 256 + lane * 4];
        cmax[c] = (f32x4)(-INFINITY);
    }

    const float* rowbase = simG + (size_t)(bbl * Nn + row0) * Mm + col0;
    f32x4 cur[4], nxt[4];
#pragma unroll
    for (int c = 0; c < 4; ++c)
        cur[c] = __builtin_nontemporal_load((const f32x4*)&rowbase[c * 256 + lane * 4]);

    for (int r = 0; r < 4; ++r) {
        if (r < 3) {
            const float* nrow = rowbase + (size_t)(r + 1) * Mm;
#pragma unroll
            for (int c = 0; c < 4; ++c)
                nxt[c] = __builtin_nontemporal_load((const f32x4*)&nrow[c * 256 + lane * 4]);
        }
        const int n = bb * Nn + row0 + r;
        const float Ln = Lrow[n];
        const float cbias = -40.f - Ln;
        float bk = -INFINITY, bc = -INFINITY;
        int bm = 0x7fffffff;
#pragma unroll
        for (int c = 0; c < 4; ++c) {
            float cv0 = fmaf(40.f, cur[c].x, cbias);
            float cv1 = fmaf(40.f, cur[c].y, cbias);
            float cv2 = fmaf(40.f, cur[c].z, cbias);
            float cv3 = fmaf(40.f, cur[c].w, cbias);
            cmax[c].x = fmaxf(cmax[c].x, cv0);
            cmax[c].y = fmaxf(cmax[c].y, cv1);
            cmax[c].z = fmaxf(cmax[c].z, cv2);
            cmax[c].w = fmaxf(cmax[c].w, cv3);
            const int mb = col0 + c * 256 + lane * 4;
            float kv0 = cv0 - Lc4[c].x;
            float kv1 = cv1 - Lc4[c].y;
            float kv2 = cv2 - Lc4[c].z;
            float kv3 = cv3 - Lc4[c].w;
            if (kv0 > bk) { bk = kv0; bm = mb;     bc = cv0; }
            if (kv1 > bk) { bk = kv1; bm = mb + 1; bc = cv1; }
            if (kv2 > bk) { bk = kv2; bm = mb + 2; bc = cv2; }
            if (kv3 > bk) { bk = kv3; bm = mb + 3; bc = cv3; }
        }
#pragma unroll
        for (int sh = 1; sh < 64; sh <<= 1) {
            float okv = __shfl_xor(bk, sh, 64);
            int   om  = __shfl_xor(bm, sh, 64);
            float ocv = __shfl_xor(bc, sh, 64);
            if (okv > bk || (okv == bk && om < bm)) { bk = okv; bm = om; bc = ocv; }
        }
        if (lane == 0) {
            size_t o = ((size_t)bb * Nn + row0 + r) * 4 + q;
            kvP[o] = bk; cvP[o] = bc; jP[o] = bm;
        }
#pragma unroll
        for (int c = 0; c < 4; ++c) cur[c] = nxt[c];
    }
    // merge the 4 waves' (16 rows') colmax in LDS, then straight to global
#pragma unroll
    for (int c = 0; c < 4; ++c) {
        const int mb = c * 256 + lane * 4;
        atomicMax(&colu[mb],     encf(cmax[c].x));
        atomicMax(&colu[mb + 1], encf(cmax[c].y));
        atomicMax(&colu[mb + 2], encf(cmax[c].z));
        atomicMax(&colu[mb + 3], encf(cmax[c].w));
    }
    __syncthreads();
    unsigned* cm = colMaxU + (size_t)bb * Mm + col0;
    for (int i = t; i < 1024; i += 256) atomicMax(&cm[i], colu[i]);
}

// ---------------- validate rows: merge 4 quarter-candidates, gate ----------------
__global__ __launch_bounds__(256) void validate_kernel(
    const float* __restrict__ kvP, const float* __restrict__ cvP,
    const int* __restrict__ jP, const unsigned* __restrict__ colMaxU,
    float* __restrict__ outJ, int* __restrict__ jIdx, int* __restrict__ v1)
{
    const float LOG_THR = -4.605170185988091f;   // ln(0.01)
    const int p = blockIdx.x * 256 + threadIdx.x;
    const int bb = p >> 12;
    float bk = -INFINITY, bc = -INFINITY;
    int bm = 0x7fffffff;
#pragma unroll
    for (int q = 0; q < 4; ++q) {
        size_t o = (size_t)p * 4 + q;
        float k = kvP[o];
        int   m = jP[o];
        if (k > bk || (k == bk && m < bm)) { bk = k; bm = m; bc = cvP[o]; }
    }
    const float cm = decf(colMaxU[(size_t)bb * Mm + bm]);
    const int ok = (bk > LOG_THR) && (bc >= cm);
    outJ[p] = (float)bm;
    jIdx[p] = bm;
    v1[p] = ok;
}

// ---------------- finalize rows (fallback path) ----------------
__global__ __launch_bounds__(256) void finalize_kernel(
    const float* __restrict__ rkey, const int* __restrict__ rmArr,
    const float* __restrict__ rcvArr, const unsigned* __restrict__ cmU,
    float* __restrict__ outJ, int* __restrict__ jIdx, int* __restrict__ v1)
{
    const float LOG_THR = -4.605170185988091f;
    int p = blockIdx.x * 256 + threadIdx.x;
    int bb = p >> 12, n = p & 4095;
    float bk = -INFINITY, bc = -INFINITY;
    int bm = 0;
    for (int mt = 0; mt < 32; ++mt) {
        size_t idx = (size_t)(bb * 32 + mt) * Nn + n;
        float k = rkey[idx];
        if (k > bk) { bk = k; bm = rmArr[idx]; bc = rcvArr[idx]; }
    }
    unsigned u = 0u;
    for (int nt = 0; nt < 16; ++nt) {
        unsigned c = cmU[(size_t)(bb * 16 + nt) * Mm + bm];
        if (c > u) u = c;
    }
    float cm = decf(u);
    int ok = (bk > LOG_THR) && (bc >= cm);
    outJ[p] = (float)bm;
    jIdx[p] = bm;
    v1[p]   = ok;
}

// ---------------- affine head ----------------
__global__ __launch_bounds__(256) void affine_kernel(
    const float* __restrict__ descA, const float* __restrict__ descB,
    const float* __restrict__ kpA, const float* __restrict__ kpB,
    const float* __restrict__ W, const float* __restrict__ bvec,
    const int* __restrict__ jIdx, const int* __restrict__ v1,
    float* __restrict__ outA, float* __restrict__ outB, float* __restrict__ outV)
{
    __shared__ float Ws[D0c * Kc];
    __shared__ float sbuf[4][4][D0c];
    const int t = threadIdx.x, wave = t >> 6, lane = t & 63;
    for (int i = t; i < D0c * Kc; i += 256) Ws[i] = W[i];
    const float bl = bvec[lane];
    __syncthreads();

    float* s0A = sbuf[wave][0];
    float* s1A = sbuf[wave][1];
    float* s0B = sbuf[wave][2];
    float* s1B = sbuf[wave][3];

    for (int p = 0; p < 8; ++p) {
        const int point = blockIdx.x * 32 + wave * 8 + p;
        const int bb = point >> 12;
        const int j = jIdx[point];
        const float* da = descA + (size_t)point * Dd;
        const float* db = descB + (size_t)(bb * Mm + j) * Dd;
        s0A[lane] = da[lane];       s0A[64 + lane] = da[64 + lane];
        s1A[lane] = da[128 + lane]; s1A[64 + lane] = da[192 + lane];
        s0B[lane] = db[lane];       s0B[64 + lane] = db[64 + lane];
        s1B[lane] = db[128 + lane]; s1B[64 + lane] = db[192 + lane];
        __syncthreads();

        float xa = bl, xb = bl;
#pragma unroll 8
        for (int d = 0; d < 128; ++d) {
            float w_ = Ws[d * 64 + lane];
            xa = fmaf(s0A[d], w_, xa);
            xb = fmaf(s0B[d], w_, xb);
        }
        float wa = softplusf(xa), wb = softplusf(xb);
        float w = sqrtf(wa * wb);
        float x0 = s1A[2 * lane], x1 = s1A[2 * lane + 1];
        float y0 = s1B[2 * lane], y1 = s1B[2 * lane + 1];
        float g00 = w * x0 * x0, g01 = w * x0 * x1, g11 = w * x1 * x1;
        float c00 = w * y0 * x0, c01 = w * y0 * x1;
        float c10 = w * y1 * x0, c11 = w * y1 * x1;
#pragma unroll
        for (int m = 32; m; m >>= 1) {
            g00 += __shfl_xor(g00, m, 64); g01 += __shfl_xor(g01, m, 64); g11 += __shfl_xor(g11, m, 64);
            c00 += __shfl_xor(c00, m, 64); c01 += __shfl_xor(c01, m, 64);
            c10 += __shfl_xor(c10, m, 64); c11 += __shfl_xor(c11, m, 64);
        }
        if (lane == 0) {
            g00 += 1e-6f; g11 += 1e-6f;
            float det = g00 * g11 - g01 * g01;
            float e00 = (c00 * g11 - c01 * g01) / det;
            float e01 = (c01 * g00 - c00 * g01) / det;
            float e10 = (c10 * g11 - c11 * g01) / det;
            float e11 = (c11 * g00 - c10 * g01) / det;
            float m00 = e00 * e00 + e10 * e10;
            float m01 = e00 * e01 + e10 * e11;
            float m11 = e01 * e01 + e11 * e11;
            float tr = m00 + m11;
            float dm = m00 * m11 - m01 * m01;
            float disc = sqrtf(fmaxf(0.25f * tr * tr - dm, 0.f));
            float lhi = 0.5f * tr + disc;
            float llo = fmaxf(0.5f * tr - disc, 0.f);
            float shi = sqrtf(lhi), slo = sqrtf(llo);
            float sdet = e00 * e11 - e01 * e10;
            int good = isfinite(shi + slo) && (shi < 3.0f) && (slo > 0.33333334f) && (sdet > 0.f);
            int valid = v1[point] && good;
            outA[2 * point]     = kpA[2 * point];
            outA[2 * point + 1] = kpA[2 * point + 1];
            const float* kb = kpB + (size_t)(bb * Mm + j) * 2;
            outB[2 * point]     = kb[0];
            outB[2 * point + 1] = kb[1];
            outV[point] = valid ? 1.f : 0.f;
        }
        __syncthreads();
    }
}

extern "C" void kernel_launch(void* const* d_in, const int* in_sizes, int n_in,
                              void* d_out, int out_size, void* d_ws, size_t ws_size,
                              hipStream_t stream) {
    const float* kpA = (const float*)d_in[0];
    const float* dA  = (const float*)d_in[1];
    const float* kpB = (const float*)d_in[2];
    const float* dB  = (const float*)d_in[3];
    const float* W   = (const float*)d_in[4];
    const float* bl  = (const float*)d_in[5];
    float* out = (float*)d_out;

    char* ws = (char*)d_ws;
    _Float16* Ah = (_Float16*)ws;  ws += 8388608;
    _Float16* Al = (_Float16*)ws;  ws += 8388608;
    _Float16* Bh = (_Float16*)ws;  ws += 8388608;
    _Float16* Bl = (_Float16*)ws;  ws += 8388608;
    float*    rowsumP = (float*)ws;    ws += 2097152;
    float*    colsumP = (float*)ws;    ws += 2097152;
    float*    Lrow    = (float*)ws;    ws += 65536;
    float*    Lcol    = (float*)ws;    ws += 65536;
    int*      jIdx    = (int*)ws;      ws += 65536;
    int*      v1      = (int*)ws;      ws += 65536;
    float*    kvP     = (float*)ws;    ws += 262144;
    float*    cvP     = (float*)ws;    ws += 262144;
    int*      jP      = (int*)ws;      ws += 262144;
    unsigned* colMaxU = (unsigned*)ws; ws += 65536;
    char*     big     = ws;

    const size_t base = (size_t)(big - (char*)d_ws);

    // fallback layout (overlays big region)
    float*    rkey  = (float*)big;
    int*      rmArr = (int*)(big + 2097152);
    float*    rcvArr= (float*)(big + 4194304);
    unsigned* cmU   = (unsigned*)(big + 6291456);

    float* outA = out;               // matches_A : 32768
    float* outB = out + 32768;       // matches_B : 32768
    float* outJ = out + 65536;       // j (as f32): 16384
    float* outV = out + 81920;       // valid     : 16384

    const size_t per = 67108864ull;  // CB*64 MB sim matrix
    int CB = 0;
    if      (ws_size >= base + 2 * per) CB = 2;
    else if (ws_size >= base + 1 * per) CB = 1;

    prep_kernel<<<dim3(4096, 2), 256, 0, stream>>>(dA, dB, Ah, Al, Bh, Bl, colMaxU);

    if (CB) {
        float* simG = (float*)big;
        for (int b0 = 0; b0 < Bb; b0 += CB) {
            sim_kernel<0, 1><<<512 * CB, 512, 0, stream>>>(
                Ah, Al, Bh, Bl, nullptr, nullptr, rowsumP, colsumP,
                nullptr, nullptr, nullptr, nullptr, simG, b0, CB);
            logsum_kernel<<<32 * CB, 256, 0, stream>>>(rowsumP, colsumP, Lrow, Lcol, b0, CB);
            scan_kernel<<<1024 * CB, 256, 0, stream>>>(simG, Lrow, Lcol, kvP, cvP, jP, colMaxU, b0);
        }
        validate_kernel<<<64, 256, 0, stream>>>(kvP, cvP, jP, colMaxU, outJ, jIdx, v1);
    } else {
        sim_kernel<0, 0><<<512 * Bb, 512, 0, stream>>>(
            Ah, Al, Bh, Bl, nullptr, nullptr, rowsumP, colsumP,
            nullptr, nullptr, nullptr, nullptr, nullptr, 0, 0);
        logsum_kernel<<<32 * Bb, 256, 0, stream>>>(rowsumP, colsumP, Lrow, Lcol, 0, Bb);
        sim_kernel<1, 0><<<512 * Bb, 512, 0, stream>>>(
            Ah, Al, Bh, Bl, Lrow, Lcol, nullptr, nullptr,
            rkey, rmArr, rcvArr, cmU, nullptr, 0, 0);
        finalize_kernel<<<64, 256, 0, stream>>>(rkey, rmArr, rcvArr, cmU, outJ, jIdx, v1);
    }
    affine_kernel<<<512, 256, 0, stream>>>(dA, dB, kpA, kpB, W, bl, jIdx, v1, outA, outB, outV);
}

// Round 9
// 381.962 us; speedup vs baseline: 2.6953x; 2.6953x over previous
//
#include <hip/hip_runtime.h>
#include <math.h>

#define Bb   4
#define Nn   4096
#define Mm   4096
#define Dd   256
#define D0c  128
#define Kc   64

typedef _Float16 half8 __attribute__((ext_vector_type(8)));
typedef float    f32x4 __attribute__((ext_vector_type(4)));

__device__ __forceinline__ unsigned encf(float f) {
    unsigned u = __float_as_uint(f);
    return (u & 0x80000000u) ? ~u : (u | 0x80000000u);
}
__device__ __forceinline__ float decf(unsigned u) {
    return (u & 0x80000000u) ? __uint_as_float(u ^ 0x80000000u) : __uint_as_float(~u);
}
__device__ __forceinline__ float softplusf(float x) {
    return fmaxf(x, 0.f) + log1pf(expf(-fabsf(x)));
}
__device__ __forceinline__ void gl_lds16(const _Float16* g, _Float16* l) {
    __builtin_amdgcn_global_load_lds((const __attribute__((address_space(1))) void*)g,
                                     (__attribute__((address_space(3))) void*)l, 16, 0, 0);
}

// Block->tile decode for 256x128 tiles: grid = 32 mt x 16 nt per batch (512 blocks).
// swz=2: CB==2 (1024 blocks) XCD-chunked: xcd owns an 8mt x 8nt super-tile
// (panels: 1 MB B + 2 MB A -> 3 MB < 4 MB XCD L2).
// swz=1: CB==1 (512 blocks). swz=0: plain linear (fallback).
__device__ __forceinline__ void decode_tile(int bid, int swz, int& mt, int& nt, int& zz) {
    if (swz == 2) {
        const int xcd = bid & 7, k = bid >> 3;   // k in 0..127
        zz = k >> 6;
        const int kk = k & 63;
        mt = (xcd & 3) * 8 + (kk & 7);
        nt = (xcd >> 2) * 8 + (kk >> 3);
    } else if (swz == 1) {
        const int xcd = bid & 7, k = bid >> 3;   // k in 0..63
        zz = 0;
        mt = (xcd & 3) * 8 + (k & 7);
        nt = (xcd >> 2) * 8 + (k >> 3);
    } else {
        mt = bid & 31; nt = (bid >> 5) & 15; zz = bid >> 9;
    }
}

// ---------------- prep: normalize rows, split fp16 hi/lo, tiled layout -------------
// lo part stored UNSCALED (x - h): correction MFMAs accumulate into the same fp32
// accumulator as h*h. Also zero-inits the persistent per-batch column-max buffer.
__global__ __launch_bounds__(256) void prep_kernel(
    const float* __restrict__ dA, const float* __restrict__ dB,
    _Float16* __restrict__ Ah, _Float16* __restrict__ Al,
    _Float16* __restrict__ Bh, _Float16* __restrict__ Bl,
    unsigned* __restrict__ colMaxU)
{
    const int t = threadIdx.x, wave = t >> 6, lane = t & 63;
    const int row = blockIdx.x * 4 + wave;           // 0..16383
    if (blockIdx.y == 0 && lane == 0) colMaxU[row] = 0u;
    const float* src = blockIdx.y ? dB : dA;
    _Float16* dh = blockIdx.y ? Bh : Ah;
    _Float16* dl = blockIdx.y ? Bl : Al;
    const float4 v = *(const float4*)&src[(size_t)row * Dd + lane * 4];
    float ss = v.x * v.x + v.y * v.y + v.z * v.z + v.w * v.w;
#pragma unroll
    for (int m = 32; m; m >>= 1) ss += __shfl_xor(ss, m, 64);
    const float inv = 1.0f / sqrtf(ss);
    float x[4] = {v.x * inv, v.y * inv, v.z * inv, v.w * inv};
    union { _Float16 h[4]; uint2 u; } ph, pl;
#pragma unroll
    for (int i = 0; i < 4; i++) {
        _Float16 h = (_Float16)x[i];
        ph.h[i] = h;
        pl.h[i] = (_Float16)(x[i] - (float)h);    // unscaled residual
    }
    const size_t toff = (size_t)(row >> 7) * 32768
                      + (size_t)(lane >> 3) * 4096
                      + (size_t)((lane >> 1) & 3) * 1024
                      + (size_t)(row & 127) * 8 + (lane & 1) * 4;
    *(uint2*)&dh[toff] = ph.u;
    *(uint2*)&dl[toff] = pl.u;
}

// ---------------- MFMA sim kernel: 256x128 tile, 8 waves (4x2 grid of 64x64) -------
// 16x16x32 MFMA. Staging LDS 48 KB/k-step (Ah 16K | Al 16K | Bh 8K | Bl 8K);
// epilogue buffers ALIAS the staging region. __launch_bounds__(512,4): 128-VGPR cap
// (r8's (512,6)=84-cap spilled the 64-reg accumulator to scratch -> 1.27 GB writes).
// A layout per array: [quad][grp2][128][8] halfs; B: [quad][128][8].
// PB=0: row/col exp-sum partials + optional NT STORE. PB=1: argmax (fallback only).
template<int PB, int STORE>
__global__ __launch_bounds__(512, 4) void sim_kernel(
    const _Float16* __restrict__ Ah, const _Float16* __restrict__ Al,
    const _Float16* __restrict__ Bh, const _Float16* __restrict__ Bl,
    const float* __restrict__ Lrow_g, const float* __restrict__ Lcol_g,
    float* __restrict__ rowsumP, float* __restrict__ colsumP,
    float* __restrict__ rkey, int* __restrict__ rmArr, float* __restrict__ rcvArr,
    unsigned* __restrict__ cmU, float* __restrict__ simG, int b0, int swz)
{
    __shared__ _Float16 S[24576];               // 48 KB staging (+aliased epilogue)

    const int t = threadIdx.x;
    const int wave = t >> 6, lane = t & 63;
    const int wr = wave >> 1, wc = wave & 1;    // 4x2 wave grid, 64x64 each
    const int quad = lane >> 4, l15 = lane & 15;
    int mt, nt, bbl;
    decode_tile(blockIdx.x, swz, mt, nt, bbl);
    const int bb = b0 + bbl;
    const int n0 = nt * 256, m0 = mt * 128;

    const _Float16* gAh = Ah + (size_t)(bb * 32 + nt * 2) * 32768;
    const _Float16* gAl = Al + (size_t)(bb * 32 + nt * 2) * 32768;
    const _Float16* gBh = Bh + (size_t)(bb * 32 + mt) * 32768;
    const _Float16* gBl = Bl + (size_t)(bb * 32 + mt) * 32768;

    f32x4 acc[4][4];                            // [ti][tj]
#pragma unroll
    for (int ti = 0; ti < 4; ti++)
#pragma unroll
        for (int tj = 0; tj < 4; tj++) acc[ti][tj] = (f32x4)0.f;

    const int grpA = wr >> 1;                   // A group (rows 0-127 / 128-255)
    const int arl = (wr & 1) * 64;              // row base within group

    for (int kc8 = 0; kc8 < 8; ++kc8) {
        // stage 48 chunks of 1 KB; wave w stages chunks w*6 .. w*6+5
#pragma unroll
        for (int q = 0; q < 6; ++q) {
            const int c = wave * 6 + q;
            _Float16* dst = S + c * 512;
            const _Float16* src;
            if (c < 32) {                       // A arrays: 16 chunks each
                const int ca = c & 15;          // [quad=ca>>2][grp=(ca>>1)&1][rh=ca&1]
                const _Float16* gA = (c < 16) ? gAh : gAl;
                src = gA + ((ca >> 1) & 1) * 32768 + kc8 * 4096
                        + (ca >> 2) * 1024 + (ca & 1) * 512;
            } else {                            // B arrays: 8 chunks each
                const int cb = c & 7;           // [quad=cb>>1][rh=cb&1]
                const _Float16* gB = (c < 40) ? gBh : gBl;
                src = gB + kc8 * 4096 + (cb >> 1) * 1024 + (cb & 1) * 512;
            }
            gl_lds16(src + lane * 8, dst);
        }
        __syncthreads();

        half8 afh[4], afl[4];
#pragma unroll
        for (int ti = 0; ti < 4; ++ti) {
            const int r8 = (arl + ti * 16 + l15) * 8;
            afh[ti] = *(const half8*)&S[        quad * 2048 + grpA * 1024 + r8];
            afl[ti] = *(const half8*)&S[8192 + quad * 2048 + grpA * 1024 + r8];
        }
#pragma unroll
        for (int tj = 0; tj < 4; ++tj) {
            const int c8 = (wc * 64 + tj * 16 + l15) * 8;
            half8 bh = *(const half8*)&S[16384 + quad * 1024 + c8];
            half8 bl = *(const half8*)&S[20480 + quad * 1024 + c8];
#pragma unroll
            for (int ti = 0; ti < 4; ++ti) {
                acc[ti][tj] = __builtin_amdgcn_mfma_f32_16x16x32_f16(afh[ti], bh, acc[ti][tj], 0, 0, 0);
                acc[ti][tj] = __builtin_amdgcn_mfma_f32_16x16x32_f16(afh[ti], bl, acc[ti][tj], 0, 0, 0);
                acc[ti][tj] = __builtin_amdgcn_mfma_f32_16x16x32_f16(afl[ti], bh, acc[ti][tj], 0, 0, 0);
            }
        }
        __syncthreads();
    }

    if (!PB) {
        float* rowpS = (float*)S;               // 256 (aliases dead staging)
        float* colpS = (float*)S + 256;         // 128
        if (t < 256) rowpS[t] = 0.f;
        if (t < 128) colpS[t] = 0.f;
        __syncthreads();

        float rp[16], cp[4] = {0.f, 0.f, 0.f, 0.f};
#pragma unroll
        for (int i = 0; i < 16; ++i) rp[i] = 0.f;
#pragma unroll
        for (int ti = 0; ti < 4; ++ti)
#pragma unroll
            for (int tj = 0; tj < 4; ++tj)
#pragma unroll
                for (int r = 0; r < 4; ++r) {
                    float e = __expf(fmaf(20.f, acc[ti][tj][r], -20.f));
                    rp[ti * 4 + r] += e;
                    cp[tj] += e;
                }
#pragma unroll
        for (int i = 0; i < 16; ++i)
#pragma unroll
            for (int m = 1; m < 16; m <<= 1) rp[i] += __shfl_xor(rp[i], m, 64);
        if (l15 == 0) {
#pragma unroll
            for (int ti = 0; ti < 4; ++ti)
#pragma unroll
                for (int r = 0; r < 4; ++r)
                    atomicAdd(&rowpS[wr * 64 + ti * 16 + quad * 4 + r], rp[ti * 4 + r]);
        }
#pragma unroll
        for (int tj = 0; tj < 4; ++tj) {
            cp[tj] += __shfl_xor(cp[tj], 16, 64);
            cp[tj] += __shfl_xor(cp[tj], 32, 64);
        }
        if (quad == 0) {
#pragma unroll
            for (int tj = 0; tj < 4; ++tj) atomicAdd(&colpS[wc * 64 + tj * 16 + l15], cp[tj]);
        }
        __syncthreads();
        if (t < 256) rowsumP[(size_t)(bb * 32 + mt) * Nn + n0 + t] = rowpS[t];
        if (t < 128) colsumP[(size_t)(bb * 16 + nt) * Mm + m0 + t] = colpS[t];
        if (STORE) {
            // nontemporal: stream to HBM, keep L2 clean for the staged panels
            float* base = simG + ((size_t)bbl * Nn + n0) * Mm + m0 + wc * 64;
#pragma unroll
            for (int ti = 0; ti < 4; ++ti)
#pragma unroll
                for (int r = 0; r < 4; ++r) {
                    float* rowp_ = base + (size_t)(wr * 64 + ti * 16 + quad * 4 + r) * Mm;
#pragma unroll
                    for (int tj = 0; tj < 4; ++tj)
                        __builtin_nontemporal_store(acc[ti][tj][r], rowp_ + tj * 16 + l15);
                }
        }
    } else {
        float*    shL  = (float*)S;                    // 256
        float*    shLc = (float*)S + 256;              // 128
        float*    s_bk = (float*)S + 384;              // 256
        float*    s_bc = (float*)S + 640;              // 256
        int*      s_bm = (int*)((float*)S + 896);      // 256
        unsigned* colu = (unsigned*)((float*)S + 1152);// 128
        if (t < 256) shL[t] = Lrow_g[bb * Nn + n0 + t];
        if (t < 128) { shLc[t] = Lcol_g[bb * Mm + m0 + t]; colu[t] = 0u; }
        __syncthreads();

        float Lr[16];
#pragma unroll
        for (int ti = 0; ti < 4; ++ti)
#pragma unroll
            for (int r = 0; r < 4; ++r)
                Lr[ti * 4 + r] = shL[wr * 64 + ti * 16 + quad * 4 + r];

        float bk[16], bc[16];
        int bm[16];
        unsigned cu[4];
#pragma unroll
        for (int i = 0; i < 16; i++) { bk[i] = -INFINITY; bc[i] = -INFINITY; bm[i] = 0x7fffffff; }
#pragma unroll
        for (int j = 0; j < 4; j++) cu[j] = 0u;

#pragma unroll
        for (int ti = 0; ti < 4; ++ti)
#pragma unroll
            for (int tj = 0; tj < 4; ++tj)
#pragma unroll
                for (int r = 0; r < 4; ++r) {
                    float cv = fmaf(40.f, acc[ti][tj][r], -40.f - Lr[ti * 4 + r]);
                    float kv = cv - shLc[wc * 64 + tj * 16 + l15];
                    const int i = ti * 4 + r;
                    if (kv > bk[i]) { bk[i] = kv; bm[i] = m0 + wc * 64 + tj * 16 + l15; bc[i] = cv; }
                    unsigned e = encf(cv);
                    if (e > cu[tj]) cu[tj] = e;
                }
#pragma unroll
        for (int i = 0; i < 16; ++i) {
#pragma unroll
            for (int m = 1; m < 16; m <<= 1) {
                float okv = __shfl_xor(bk[i], m, 64);
                int   om  = __shfl_xor(bm[i], m, 64);
                float ocv = __shfl_xor(bc[i], m, 64);
                if (okv > bk[i] || (okv == bk[i] && om < bm[i])) { bk[i] = okv; bm[i] = om; bc[i] = ocv; }
            }
        }
        if (l15 == 0 && wc == 0) {
#pragma unroll
            for (int ti = 0; ti < 4; ++ti)
#pragma unroll
                for (int r = 0; r < 4; ++r) {
                    const int row = wr * 64 + ti * 16 + quad * 4 + r, i = ti * 4 + r;
                    s_bk[row] = bk[i]; s_bm[row] = bm[i]; s_bc[row] = bc[i];
                }
        }
#pragma unroll
        for (int tj = 0; tj < 4; ++tj) {
            unsigned o = __shfl_xor(cu[tj], 16, 64); if (o > cu[tj]) cu[tj] = o;
            o = __shfl_xor(cu[tj], 32, 64); if (o > cu[tj]) cu[tj] = o;
        }
        if (quad == 0) {
#pragma unroll
            for (int tj = 0; tj < 4; ++tj) atomicMax(&colu[wc * 64 + tj * 16 + l15], cu[tj]);
        }
        __syncthreads();
        if (l15 == 0 && wc == 1) {
#pragma unroll
            for (int ti = 0; ti < 4; ++ti)
#pragma unroll
                for (int r = 0; r < 4; ++r) {
                    const int row = wr * 64 + ti * 16 + quad * 4 + r, i = ti * 4 + r;
                    float k0 = s_bk[row];
                    if (bk[i] > k0 || (bk[i] == k0 && bm[i] < s_bm[row])) {
                        s_bk[row] = bk[i]; s_bm[row] = bm[i]; s_bc[row] = bc[i];
                    }
                }
        }
        __syncthreads();
        if (t < 256) {
            size_t idx = (size_t)(bb * 32 + mt) * Nn + n0 + t;
            rkey[idx] = s_bk[t]; rmArr[idx] = s_bm[t]; rcvArr[idx] = s_bc[t];
        }
        if (t < 128) cmU[(size_t)(bb * 16 + nt) * Mm + m0 + t] = colu[t];
    }
}

// ---------------- reduce partials -> L = log(rowsum), Lc = log(colsum), chunked -----
// rows: 32 mt-partials; cols: 16 nt-partials (256-row tiles).
__global__ __launch_bounds__(256) void logsum_kernel(
    const float* __restrict__ rowsumP, const float* __restrict__ colsumP,
    float* __restrict__ Lrow, float* __restrict__ Lcol, int b0, int CB)
{
    int t = blockIdx.x * 256 + threadIdx.x;
    int half = CB * 4096;
    int which = t >= half;
    int idx = which ? (t - half) : t;
    int bb = b0 + (idx >> 12), n = idx & 4095;
    float s = 0.f;
    if (which) {
        for (int nt = 0; nt < 16; ++nt) s += colsumP[(size_t)(bb * 16 + nt) * 4096 + n];
        Lcol[bb * 4096 + n] = logf(s);
    } else {
        for (int mt = 0; mt < 32; ++mt) s += rowsumP[(size_t)(bb * 32 + mt) * 4096 + n];
        Lrow[bb * 4096 + n] = logf(s);
    }
}

// ---------------- scan: block = 16 rows x 1024 cols (quarter), NT loads ------------
// Column-max goes straight to the persistent per-batch colMaxU via global atomicMax.
__global__ __launch_bounds__(256) void scan_kernel(
    const float* __restrict__ simG,
    const float* __restrict__ Lrow, const float* __restrict__ Lcol,
    float* __restrict__ kvP, float* __restrict__ cvP, int* __restrict__ jP,
    unsigned* __restrict__ colMaxU, int b0)
{
    __shared__ unsigned colu[1024];          // 4 KB
    const int t = threadIdx.x, wave = t >> 6, lane = t & 63;
    const int blk = blockIdx.x;              // 0 .. CB*1024-1
    const int bbl = blk >> 10;
    const int r10 = blk & 1023;
    const int stripe = r10 >> 2, q = r10 & 3;   // 256 stripes of 16 rows; col quarter
    const int bb = b0 + bbl;
    const int col0 = q * 1024;
    const int row0 = stripe * 16 + wave * 4;

    for (int i = t; i < 1024; i += 256) colu[i] = 0u;
    __syncthreads();

    f32x4 Lc4[4], cmax[4];
    const float* LcB = Lcol + bb * Mm + col0;
#pragma unroll
    for (int c = 0; c < 4; ++c) {
        Lc4[c] = *(const f32x4*)&LcB[c * 256 + lane * 4];
        cmax[c] = (f32x4)(-INFINITY);
    }

    const float* rowbase = simG + (size_t)(bbl * Nn + row0) * Mm + col0;
    f32x4 cur[4], nxt[4];
#pragma unroll
    for (int c = 0; c < 4; ++c)
        cur[c] = __builtin_nontemporal_load((const f32x4*)&rowbase[c * 256 + lane * 4]);

    for (int r = 0; r < 4; ++r) {
        if (r < 3) {
            const float* nrow = rowbase + (size_t)(r + 1) * Mm;
#pragma unroll
            for (int c = 0; c < 4; ++c)
                nxt[c] = __builtin_nontemporal_load((const f32x4*)&nrow[c * 256 + lane * 4]);
        }
        const int n = bb * Nn + row0 + r;
        const float Ln = Lrow[n];
        const float cbias = -40.f - Ln;
        float bk = -INFINITY, bc = -INFINITY;
        int bm = 0x7fffffff;
#pragma unroll
        for (int c = 0; c < 4; ++c) {
            float cv0 = fmaf(40.f, cur[c].x, cbias);
            float cv1 = fmaf(40.f, cur[c].y, cbias);
            float cv2 = fmaf(40.f, cur[c].z, cbias);
            float cv3 = fmaf(40.f, cur[c].w, cbias);
            cmax[c].x = fmaxf(cmax[c].x, cv0);
            cmax[c].y = fmaxf(cmax[c].y, cv1);
            cmax[c].z = fmaxf(cmax[c].z, cv2);
            cmax[c].w = fmaxf(cmax[c].w, cv3);
            const int mb = col0 + c * 256 + lane * 4;
            float kv0 = cv0 - Lc4[c].x;
            float kv1 = cv1 - Lc4[c].y;
            float kv2 = cv2 - Lc4[c].z;
            float kv3 = cv3 - Lc4[c].w;
            if (kv0 > bk) { bk = kv0; bm = mb;     bc = cv0; }
            if (kv1 > bk) { bk = kv1; bm = mb + 1; bc = cv1; }
            if (kv2 > bk) { bk = kv2; bm = mb + 2; bc = cv2; }
            if (kv3 > bk) { bk = kv3; bm = mb + 3; bc = cv3; }
        }
#pragma unroll
        for (int sh = 1; sh < 64; sh <<= 1) {
            float okv = __shfl_xor(bk, sh, 64);
            int   om  = __shfl_xor(bm, sh, 64);
            float ocv = __shfl_xor(bc, sh, 64);
            if (okv > bk || (okv == bk && om < bm)) { bk = okv; bm = om; bc = ocv; }
        }
        if (lane == 0) {
            size_t o = ((size_t)bb * Nn + row0 + r) * 4 + q;
            kvP[o] = bk; cvP[o] = bc; jP[o] = bm;
        }
#pragma unroll
        for (int c = 0; c < 4; ++c) cur[c] = nxt[c];
    }
    // merge the 4 waves' (16 rows') colmax in LDS, then straight to global
#pragma unroll
    for (int c = 0; c < 4; ++c) {
        const int mb = c * 256 + lane * 4;
        atomicMax(&colu[mb],     encf(cmax[c].x));
        atomicMax(&colu[mb + 1], encf(cmax[c].y));
        atomicMax(&colu[mb + 2], encf(cmax[c].z));
        atomicMax(&colu[mb + 3], encf(cmax[c].w));
    }
    __syncthreads();
    unsigned* cm = colMaxU + (size_t)bb * Mm + col0;
    for (int i = t; i < 1024; i += 256) atomicMax(&cm[i], colu[i]);
}

// ---------------- validate rows: merge 4 quarter-candidates, gate ----------------
__global__ __launch_bounds__(256) void validate_kernel(
    const float* __restrict__ kvP, const float* __restrict__ cvP,
    const int* __restrict__ jP, const unsigned* __restrict__ colMaxU,
    float* __restrict__ outJ, int* __restrict__ jIdx, int* __restrict__ v1)
{
    const float LOG_THR = -4.605170185988091f;   // ln(0.01)
    const int p = blockIdx.x * 256 + threadIdx.x;
    const int bb = p >> 12;
    float bk = -INFINITY, bc = -INFINITY;
    int bm = 0x7fffffff;
#pragma unroll
    for (int q = 0; q < 4; ++q) {
        size_t o = (size_t)p * 4 + q;
        float k = kvP[o];
        int   m = jP[o];
        if (k > bk || (k == bk && m < bm)) { bk = k; bm = m; bc = cvP[o]; }
    }
    const float cm = decf(colMaxU[(size_t)bb * Mm + bm]);
    const int ok = (bk > LOG_THR) && (bc >= cm);
    outJ[p] = (float)bm;
    jIdx[p] = bm;
    v1[p] = ok;
}

// ---------------- finalize rows (fallback path) ----------------
__global__ __launch_bounds__(256) void finalize_kernel(
    const float* __restrict__ rkey, const int* __restrict__ rmArr,
    const float* __restrict__ rcvArr, const unsigned* __restrict__ cmU,
    float* __restrict__ outJ, int* __restrict__ jIdx, int* __restrict__ v1)
{
    const float LOG_THR = -4.605170185988091f;
    int p = blockIdx.x * 256 + threadIdx.x;
    int bb = p >> 12, n = p & 4095;
    float bk = -INFINITY, bc = -INFINITY;
    int bm = 0;
    for (int mt = 0; mt < 32; ++mt) {
        size_t idx = (size_t)(bb * 32 + mt) * Nn + n;
        float k = rkey[idx];
        if (k > bk) { bk = k; bm = rmArr[idx]; bc = rcvArr[idx]; }
    }
    unsigned u = 0u;
    for (int nt = 0; nt < 16; ++nt) {
        unsigned c = cmU[(size_t)(bb * 16 + nt) * Mm + bm];
        if (c > u) u = c;
    }
    float cm = decf(u);
    int ok = (bk > LOG_THR) && (bc >= cm);
    outJ[p] = (float)bm;
    jIdx[p] = bm;
    v1[p]   = ok;
}

// ---------------- affine head ----------------
__global__ __launch_bounds__(256) void affine_kernel(
    const float* __restrict__ descA, const float* __restrict__ descB,
    const float* __restrict__ kpA, const float* __restrict__ kpB,
    const float* __restrict__ W, const float* __restrict__ bvec,
    const int* __restrict__ jIdx, const int* __restrict__ v1,
    float* __restrict__ outA, float* __restrict__ outB, float* __restrict__ outV)
{
    __shared__ float Ws[D0c * Kc];
    __shared__ float sbuf[4][4][D0c];
    const int t = threadIdx.x, wave = t >> 6, lane = t & 63;
    for (int i = t; i < D0c * Kc; i += 256) Ws[i] = W[i];
    const float bl = bvec[lane];
    __syncthreads();

    float* s0A = sbuf[wave][0];
    float* s1A = sbuf[wave][1];
    float* s0B = sbuf[wave][2];
    float* s1B = sbuf[wave][3];

    for (int p = 0; p < 8; ++p) {
        const int point = blockIdx.x * 32 + wave * 8 + p;
        const int bb = point >> 12;
        const int j = jIdx[point];
        const float* da = descA + (size_t)point * Dd;
        const float* db = descB + (size_t)(bb * Mm + j) * Dd;
        s0A[lane] = da[lane];       s0A[64 + lane] = da[64 + lane];
        s1A[lane] = da[128 + lane]; s1A[64 + lane] = da[192 + lane];
        s0B[lane] = db[lane];       s0B[64 + lane] = db[64 + lane];
        s1B[lane] = db[128 + lane]; s1B[64 + lane] = db[192 + lane];
        __syncthreads();

        float xa = bl, xb = bl;
#pragma unroll 8
        for (int d = 0; d < 128; ++d) {
            float w_ = Ws[d * 64 + lane];
            xa = fmaf(s0A[d], w_, xa);
            xb = fmaf(s0B[d], w_, xb);
        }
        float wa = softplusf(xa), wb = softplusf(xb);
        float w = sqrtf(wa * wb);
        float x0 = s1A[2 * lane], x1 = s1A[2 * lane + 1];
        float y0 = s1B[2 * lane], y1 = s1B[2 * lane + 1];
        float g00 = w * x0 * x0, g01 = w * x0 * x1, g11 = w * x1 * x1;
        float c00 = w * y0 * x0, c01 = w * y0 * x1;
        float c10 = w * y1 * x0, c11 = w * y1 * x1;
#pragma unroll
        for (int m = 32; m; m >>= 1) {
            g00 += __shfl_xor(g00, m, 64); g01 += __shfl_xor(g01, m, 64); g11 += __shfl_xor(g11, m, 64);
            c00 += __shfl_xor(c00, m, 64); c01 += __shfl_xor(c01, m, 64);
            c10 += __shfl_xor(c10, m, 64); c11 += __shfl_xor(c11, m, 64);
        }
        if (lane == 0) {
            g00 += 1e-6f; g11 += 1e-6f;
            float det = g00 * g11 - g01 * g01;
            float e00 = (c00 * g11 - c01 * g01) / det;
            float e01 = (c01 * g00 - c00 * g01) / det;
            float e10 = (c10 * g11 - c11 * g01) / det;
            float e11 = (c11 * g00 - c10 * g01) / det;
            float m00 = e00 * e00 + e10 * e10;
            float m01 = e00 * e01 + e10 * e11;
            float m11 = e01 * e01 + e11 * e11;
            float tr = m00 + m11;
            float dm = m00 * m11 - m01 * m01;
            float disc = sqrtf(fmaxf(0.25f * tr * tr - dm, 0.f));
            float lhi = 0.5f * tr + disc;
            float llo = fmaxf(0.5f * tr - disc, 0.f);
            float shi = sqrtf(lhi), slo = sqrtf(llo);
            float sdet = e00 * e11 - e01 * e10;
            int good = isfinite(shi + slo) && (shi < 3.0f) && (slo > 0.33333334f) && (sdet > 0.f);
            int valid = v1[point] && good;
            outA[2 * point]     = kpA[2 * point];
            outA[2 * point + 1] = kpA[2 * point + 1];
            const float* kb = kpB + (size_t)(bb * Mm + j) * 2;
            outB[2 * point]     = kb[0];
            outB[2 * point + 1] = kb[1];
            outV[point] = valid ? 1.f : 0.f;
        }
        __syncthreads();
    }
}

extern "C" void kernel_launch(void* const* d_in, const int* in_sizes, int n_in,
                              void* d_out, int out_size, void* d_ws, size_t ws_size,
                              hipStream_t stream) {
    const float* kpA = (const float*)d_in[0];
    const float* dA  = (const float*)d_in[1];
    const float* kpB = (const float*)d_in[2];
    const float* dB  = (const float*)d_in[3];
    const float* W   = (const float*)d_in[4];
    const float* bl  = (const float*)d_in[5];
    float* out = (float*)d_out;

    char* ws = (char*)d_ws;
    _Float16* Ah = (_Float16*)ws;  ws += 8388608;
    _Float16* Al = (_Float16*)ws;  ws += 8388608;
    _Float16* Bh = (_Float16*)ws;  ws += 8388608;
    _Float16* Bl = (_Float16*)ws;  ws += 8388608;
    float*    rowsumP = (float*)ws;    ws += 2097152;
    float*    colsumP = (float*)ws;    ws += 2097152;
    float*    Lrow    = (float*)ws;    ws += 65536;
    float*    Lcol    = (float*)ws;    ws += 65536;
    int*      jIdx    = (int*)ws;      ws += 65536;
    int*      v1      = (int*)ws;      ws += 65536;
    float*    kvP     = (float*)ws;    ws += 262144;
    float*    cvP     = (float*)ws;    ws += 262144;
    int*      jP      = (int*)ws;      ws += 262144;
    unsigned* colMaxU = (unsigned*)ws; ws += 65536;
    char*     big     = ws;

    const size_t base = (size_t)(big - (char*)d_ws);

    // fallback layout (overlays big region)
    float*    rkey  = (float*)big;
    int*      rmArr = (int*)(big + 2097152);
    float*    rcvArr= (float*)(big + 4194304);
    unsigned* cmU   = (unsigned*)(big + 6291456);

    float* outA = out;               // matches_A : 32768
    float* outB = out + 32768;       // matches_B : 32768
    float* outJ = out + 65536;       // j (as f32): 16384
    float* outV = out + 81920;       // valid     : 16384

    const size_t per = 67108864ull;  // CB*64 MB sim matrix
    int CB = 0;
    if      (ws_size >= base + 2 * per) CB = 2;
    else if (ws_size >= base + 1 * per) CB = 1;

    prep_kernel<<<dim3(4096, 2), 256, 0, stream>>>(dA, dB, Ah, Al, Bh, Bl, colMaxU);

    if (CB) {
        float* simG = (float*)big;
        for (int b0 = 0; b0 < Bb; b0 += CB) {
            sim_kernel<0, 1><<<512 * CB, 512, 0, stream>>>(
                Ah, Al, Bh, Bl, nullptr, nullptr, rowsumP, colsumP,
                nullptr, nullptr, nullptr, nullptr, simG, b0, CB);
            logsum_kernel<<<32 * CB, 256, 0, stream>>>(rowsumP, colsumP, Lrow, Lcol, b0, CB);
            scan_kernel<<<1024 * CB, 256, 0, stream>>>(simG, Lrow, Lcol, kvP, cvP, jP, colMaxU, b0);
        }
        validate_kernel<<<64, 256, 0, stream>>>(kvP, cvP, jP, colMaxU, outJ, jIdx, v1);
    } else {
        sim_kernel<0, 0><<<512 * Bb, 512, 0, stream>>>(
            Ah, Al, Bh, Bl, nullptr, nullptr, rowsumP, colsumP,
            nullptr, nullptr, nullptr, nullptr, nullptr, 0, 0);
        logsum_kernel<<<32 * Bb, 256, 0, stream>>>(rowsumP, colsumP, Lrow, Lcol, 0, Bb);
        sim_kernel<1, 0><<<512 * Bb, 512, 0, stream>>>(
            Ah, Al, Bh, Bl, Lrow, Lcol, nullptr, nullptr,
            rkey, rmArr, rcvArr, cmU, nullptr, 0, 0);
        finalize_kernel<<<64, 256, 0, stream>>>(rkey, rmArr, rcvArr, cmU, outJ, jIdx, v1);
    }
    affine_kernel<<<512, 256, 0, stream>>>(dA, dB, kpA, kpB, W, bl, jIdx, v1, outA, outB, outV);
}

// Round 10
// 318.307 us; speedup vs baseline: 3.2343x; 1.2000x over previous
//
#include <hip/hip_runtime.h>
#include <math.h>

#define Bb   4
#define Nn   4096
#define Mm   4096
#define Dd   256
#define D0c  128
#define Kc   64

typedef _Float16 half8 __attribute__((ext_vector_type(8)));
typedef float    f32x4 __attribute__((ext_vector_type(4)));

__device__ __forceinline__ unsigned encf(float f) {
    unsigned u = __float_as_uint(f);
    return (u & 0x80000000u) ? ~u : (u | 0x80000000u);
}
__device__ __forceinline__ float decf(unsigned u) {
    return (u & 0x80000000u) ? __uint_as_float(u ^ 0x80000000u) : __uint_as_float(~u);
}
__device__ __forceinline__ float softplusf(float x) {
    return fmaxf(x, 0.f) + log1pf(expf(-fabsf(x)));
}
__device__ __forceinline__ void gl_lds16(const _Float16* g, _Float16* l) {
    __builtin_amdgcn_global_load_lds((const __attribute__((address_space(1))) void*)g,
                                     (__attribute__((address_space(3))) void*)l, 16, 0, 0);
}

// Block->tile decode. swz=2: CB==2 XCD-chunked (2048 blocks; xcd=bid&7 owns one
// 16x16 super-tile of the 32x32 tile grid; panels = 4 MB = one XCD L2).
// swz=1: CB==1. swz=0: plain linear (fallback).
__device__ __forceinline__ void decode_tile(int bid, int swz, int& mt, int& nt, int& zz) {
    if (swz == 2) {
        const int xcd = bid & 7, k = bid >> 3;
        zz = xcd >> 2;
        const int s = xcd & 3;
        mt = (s & 1) * 16 + (k & 15);
        nt = (s >> 1) * 16 + (k >> 4);
    } else if (swz == 1) {
        const int xcd = bid & 7, k = bid >> 3;
        zz = 0;
        const int s = xcd >> 1;
        const int t = (xcd & 1) * 128 + k;
        mt = (s & 1) * 16 + (t & 15);
        nt = (s >> 1) * 16 + (t >> 4);
    } else {
        mt = bid & 31; nt = (bid >> 5) & 31; zz = bid >> 10;
    }
}

// ---------------- prep: normalize rows, split fp16 hi/lo, tiled layout -------------
// lo part stored UNSCALED (x - h): correction MFMAs accumulate into the same fp32
// accumulator as h*h. Also zero-inits the persistent per-batch column-max buffer.
__global__ __launch_bounds__(256) void prep_kernel(
    const float* __restrict__ dA, const float* __restrict__ dB,
    _Float16* __restrict__ Ah, _Float16* __restrict__ Al,
    _Float16* __restrict__ Bh, _Float16* __restrict__ Bl,
    unsigned* __restrict__ colMaxU)
{
    const int t = threadIdx.x, wave = t >> 6, lane = t & 63;
    const int row = blockIdx.x * 4 + wave;           // 0..16383
    if (blockIdx.y == 0 && lane == 0) colMaxU[row] = 0u;
    const float* src = blockIdx.y ? dB : dA;
    _Float16* dh = blockIdx.y ? Bh : Ah;
    _Float16* dl = blockIdx.y ? Bl : Al;
    const float4 v = *(const float4*)&src[(size_t)row * Dd + lane * 4];
    float ss = v.x * v.x + v.y * v.y + v.z * v.z + v.w * v.w;
#pragma unroll
    for (int m = 32; m; m >>= 1) ss += __shfl_xor(ss, m, 64);
    const float inv = 1.0f / sqrtf(ss);
    float x[4] = {v.x * inv, v.y * inv, v.z * inv, v.w * inv};
    union { _Float16 h[4]; uint2 u; } ph, pl;
#pragma unroll
    for (int i = 0; i < 4; i++) {
        _Float16 h = (_Float16)x[i];
        ph.h[i] = h;
        pl.h[i] = (_Float16)(x[i] - (float)h);    // unscaled residual
    }
    const size_t toff = (size_t)(row >> 7) * 32768
                      + (size_t)(lane >> 3) * 4096
                      + (size_t)((lane >> 1) & 3) * 1024
                      + (size_t)(row & 127) * 8 + (lane & 1) * 4;
    *(uint2*)&dh[toff] = ph.u;
    *(uint2*)&dl[toff] = pl.u;
}

// ---------------- MFMA sim kernel ----------------
// r5 structure (best measured: sim 66 us) + counted-vmcnt double-buffered staging
// (r1-r4 validated, +5.6% there): prefetch k+1 into the other 32 KB buffer before
// computing k; raw s_barrier + s_waitcnt vmcnt(8) keeps the 8 prefetch loads in
// flight across the barrier. Single merged accumulator (h*h + h*l + l*h, lo
// unscaled). 2x2 wave quadrants (64x64 per wave). XCD-chunked tile decode.
// STORE path: nontemporal (the 128 MB intermediate streams to HBM regardless).
template<int PB, int STORE>
__global__ __launch_bounds__(256, 3) void sim_kernel(
    const _Float16* __restrict__ Ah, const _Float16* __restrict__ Al,
    const _Float16* __restrict__ Bh, const _Float16* __restrict__ Bl,
    const float* __restrict__ Lrow_g, const float* __restrict__ Lcol_g,
    float* __restrict__ rowsumP, float* __restrict__ colsumP,
    float* __restrict__ rkey, int* __restrict__ rmArr, float* __restrict__ rcvArr,
    unsigned* __restrict__ cmU, float* __restrict__ simG, int b0, int swz)
{
    __shared__ _Float16 lds[2][4][4][128][8];   // 64 KB double-buffered staging
    __shared__ float    colp[128];
    __shared__ float    rowp[128];
    __shared__ unsigned colu[128];
    __shared__ float    shL[128], shLc[128];
    __shared__ float    s_bk[128], s_bc[128];
    __shared__ int      s_bm[128];

    const int t = threadIdx.x;
    const int wave = t >> 6, lane = t & 63;
    const int wr = wave >> 1, wc = wave & 1;    // 2x2 quadrant grid
    int mt, nt, bbl;
    decode_tile(blockIdx.x, swz, mt, nt, bbl);
    const int bb = b0 + bbl;
    const int n0 = nt * 128, m0 = mt * 128;

    if (PB) {
        if (t < 128) {
            shL[t]  = Lrow_g[bb * Nn + n0 + t];
            shLc[t] = Lcol_g[bb * Mm + m0 + t];
            colu[t] = 0u;
        }
    } else {
        if (t < 128) { colp[t] = 0.f; rowp[t] = 0.f; }
    }

    const _Float16* gb;
    {
        const size_t offA = (size_t)(bb * Nn + n0) * Dd;
        const size_t offB = (size_t)(bb * Mm + m0) * Dd;
        if      (wave == 0) gb = Ah + offA;
        else if (wave == 1) gb = Al + offA;
        else if (wave == 2) gb = Bh + offB;
        else                gb = Bl + offB;
    }

    f32x4 acc[4][4];                            // [ti][tj], 64x64 quadrant
#pragma unroll
    for (int ti = 0; ti < 4; ti++)
#pragma unroll
        for (int tj = 0; tj < 4; tj++) acc[ti][tj] = (f32x4)0.f;

    const int quad = lane >> 4, l15 = lane & 15;
    _Float16* lw0 = &lds[0][wave][0][0][0];
    _Float16* lw1 = &lds[1][wave][0][0][0];

    // prologue: stage k-step 0 into buffer 0
#pragma unroll
    for (int q = 0; q < 8; ++q)
        gl_lds16(gb + q * 512 + lane * 8, lw0 + q * 512);

#pragma unroll
    for (int kc8 = 0; kc8 < 8; ++kc8) {
        const int cur = kc8 & 1;
        if (kc8 < 7) {
            // prefetch k-step kc8+1 into the other buffer (safe: the end-of-
            // iteration barrier of kc8-1 guarantees all waves finished reading it)
            _Float16* nw = cur ? lw0 : lw1;
            const _Float16* gsrc = gb + (kc8 + 1) * 4096;
#pragma unroll
            for (int q = 0; q < 8; ++q)
                gl_lds16(gsrc + q * 512 + lane * 8, nw + q * 512);
            // wait only for the 8 OLDEST loads (current buffer); prefetch stays
            // in flight across the barrier
            asm volatile("s_waitcnt vmcnt(8)" ::: "memory");
        } else {
            asm volatile("s_waitcnt vmcnt(0)" ::: "memory");
        }
        __builtin_amdgcn_s_barrier();
        __builtin_amdgcn_sched_barrier(0);   // pin: no ds_read hoists above barrier

        half8 afh[4], afl[4];
#pragma unroll
        for (int ti = 0; ti < 4; ++ti) {
            afh[ti] = *(const half8*)&lds[cur][0][quad][wr * 64 + ti * 16 + l15][0];
            afl[ti] = *(const half8*)&lds[cur][1][quad][wr * 64 + ti * 16 + l15][0];
        }
#pragma unroll
        for (int tj = 0; tj < 4; ++tj) {
            half8 bh = *(const half8*)&lds[cur][2][quad][wc * 64 + tj * 16 + l15][0];
            half8 bl = *(const half8*)&lds[cur][3][quad][wc * 64 + tj * 16 + l15][0];
#pragma unroll
            for (int ti = 0; ti < 4; ++ti) {
                acc[ti][tj] = __builtin_amdgcn_mfma_f32_16x16x32_f16(afh[ti], bh, acc[ti][tj], 0, 0, 0);
                acc[ti][tj] = __builtin_amdgcn_mfma_f32_16x16x32_f16(afh[ti], bl, acc[ti][tj], 0, 0, 0);
                acc[ti][tj] = __builtin_amdgcn_mfma_f32_16x16x32_f16(afl[ti], bh, acc[ti][tj], 0, 0, 0);
            }
        }
        // all of this wave's LDS reads must be serviced before the next
        // iteration's DMA may overwrite this buffer
        asm volatile("s_waitcnt lgkmcnt(0)" ::: "memory");
        __builtin_amdgcn_s_barrier();
    }

    if (!PB) {
        float rp[16], cp[4] = {0.f, 0.f, 0.f, 0.f};
#pragma unroll
        for (int i = 0; i < 16; ++i) rp[i] = 0.f;
#pragma unroll
        for (int ti = 0; ti < 4; ++ti)
#pragma unroll
            for (int tj = 0; tj < 4; ++tj)
#pragma unroll
                for (int r = 0; r < 4; ++r) {
                    float e = __expf(fmaf(20.f, acc[ti][tj][r], -20.f));
                    rp[ti * 4 + r] += e;
                    cp[tj] += e;
                }
#pragma unroll
        for (int i = 0; i < 16; ++i)
#pragma unroll
            for (int m = 1; m < 16; m <<= 1) rp[i] += __shfl_xor(rp[i], m, 64);
        if (l15 == 0) {
#pragma unroll
            for (int ti = 0; ti < 4; ++ti)
#pragma unroll
                for (int r = 0; r < 4; ++r)
                    atomicAdd(&rowp[wr * 64 + ti * 16 + quad * 4 + r], rp[ti * 4 + r]);
        }
#pragma unroll
        for (int tj = 0; tj < 4; ++tj) {
            cp[tj] += __shfl_xor(cp[tj], 16, 64);
            cp[tj] += __shfl_xor(cp[tj], 32, 64);
        }
        if (quad == 0) {
#pragma unroll
            for (int tj = 0; tj < 4; ++tj) atomicAdd(&colp[wc * 64 + tj * 16 + l15], cp[tj]);
        }
        __syncthreads();
        if (t < 128) {
            rowsumP[(size_t)(bb * 32 + mt) * Nn + n0 + t] = rowp[t];
            colsumP[(size_t)(bb * 32 + nt) * Mm + m0 + t] = colp[t];
        }
        if (STORE) {
            // nontemporal: stream to HBM, keep L2 clean for the staged panels
            float* base = simG + ((size_t)bbl * Nn + n0) * Mm + m0 + wc * 64;
#pragma unroll
            for (int ti = 0; ti < 4; ++ti)
#pragma unroll
                for (int r = 0; r < 4; ++r) {
                    float* rowp_ = base + (size_t)(wr * 64 + ti * 16 + quad * 4 + r) * Mm;
#pragma unroll
                    for (int tj = 0; tj < 4; ++tj)
                        __builtin_nontemporal_store(acc[ti][tj][r], rowp_ + tj * 16 + l15);
                }
        }
    } else {
        float Lr[16];
#pragma unroll
        for (int ti = 0; ti < 4; ++ti)
#pragma unroll
            for (int r = 0; r < 4; ++r)
                Lr[ti * 4 + r] = shL[wr * 64 + ti * 16 + quad * 4 + r];

        float bk[16], bc[16];
        int bm[16];
        unsigned cu[4];
#pragma unroll
        for (int i = 0; i < 16; i++) { bk[i] = -INFINITY; bc[i] = -INFINITY; bm[i] = 0x7fffffff; }
#pragma unroll
        for (int j = 0; j < 4; j++) cu[j] = 0u;

#pragma unroll
        for (int ti = 0; ti < 4; ++ti)
#pragma unroll
            for (int tj = 0; tj < 4; ++tj)
#pragma unroll
                for (int r = 0; r < 4; ++r) {
                    float cv = fmaf(40.f, acc[ti][tj][r], -40.f - Lr[ti * 4 + r]);
                    float kv = cv - shLc[wc * 64 + tj * 16 + l15];
                    const int i = ti * 4 + r;
                    if (kv > bk[i]) { bk[i] = kv; bm[i] = m0 + wc * 64 + tj * 16 + l15; bc[i] = cv; }
                    unsigned e = encf(cv);
                    if (e > cu[tj]) cu[tj] = e;
                }
#pragma unroll
        for (int i = 0; i < 16; ++i) {
#pragma unroll
            for (int m = 1; m < 16; m <<= 1) {
                float okv = __shfl_xor(bk[i], m, 64);
                int   om  = __shfl_xor(bm[i], m, 64);
                float ocv = __shfl_xor(bc[i], m, 64);
                if (okv > bk[i] || (okv == bk[i] && om < bm[i])) { bk[i] = okv; bm[i] = om; bc[i] = ocv; }
            }
        }
        // cross-wc merge per row via LDS (two waves cover each row's two halves)
        if (l15 == 0 && wc == 0) {
#pragma unroll
            for (int ti = 0; ti < 4; ++ti)
#pragma unroll
                for (int r = 0; r < 4; ++r) {
                    const int row = wr * 64 + ti * 16 + quad * 4 + r, i = ti * 4 + r;
                    s_bk[row] = bk[i]; s_bm[row] = bm[i]; s_bc[row] = bc[i];
                }
        }
        __syncthreads();
        if (l15 == 0 && wc == 1) {
#pragma unroll
            for (int ti = 0; ti < 4; ++ti)
#pragma unroll
                for (int r = 0; r < 4; ++r) {
                    const int row = wr * 64 + ti * 16 + quad * 4 + r, i = ti * 4 + r;
                    float k0 = s_bk[row];
                    if (bk[i] > k0 || (bk[i] == k0 && bm[i] < s_bm[row])) {
                        s_bk[row] = bk[i]; s_bm[row] = bm[i]; s_bc[row] = bc[i];
                    }
                }
        }
#pragma unroll
        for (int tj = 0; tj < 4; ++tj) {
            unsigned o = __shfl_xor(cu[tj], 16, 64); if (o > cu[tj]) cu[tj] = o;
            o = __shfl_xor(cu[tj], 32, 64); if (o > cu[tj]) cu[tj] = o;
        }
        if (quad == 0) {
#pragma unroll
            for (int tj = 0; tj < 4; ++tj) atomicMax(&colu[wc * 64 + tj * 16 + l15], cu[tj]);
        }
        __syncthreads();
        if (t < 128) {
            size_t idx = (size_t)(bb * 32 + mt) * Nn + n0 + t;
            rkey[idx] = s_bk[t]; rmArr[idx] = s_bm[t]; rcvArr[idx] = s_bc[t];
            cmU[(size_t)(bb * 32 + nt) * Mm + m0 + t] = colu[t];
        }
    }
}

// ---------------- reduce partials -> L = log(rowsum), Lc = log(colsum), chunked -----
__global__ __launch_bounds__(256) void logsum_kernel(
    const float* __restrict__ rowsumP, const float* __restrict__ colsumP,
    float* __restrict__ Lrow, float* __restrict__ Lcol, int b0, int CB)
{
    int t = blockIdx.x * 256 + threadIdx.x;
    int half = CB * 4096;
    int which = t >= half;
    int idx = which ? (t - half) : t;
    int bb = b0 + (idx >> 12), n = idx & 4095;
    const float* P = which ? colsumP : rowsumP;
    float s = 0.f;
    for (int mt = 0; mt < 32; ++mt) s += P[(size_t)(bb * 32 + mt) * 4096 + n];
    (which ? Lcol : Lrow)[bb * 4096 + n] = logf(s);
}

// ---------------- scan: block = 16 rows x 1024 cols (quarter), NT loads ------------
// Column-max goes straight to the persistent per-batch colMaxU via global atomicMax.
__global__ __launch_bounds__(256) void scan_kernel(
    const float* __restrict__ simG,
    const float* __restrict__ Lrow, const float* __restrict__ Lcol,
    float* __restrict__ kvP, float* __restrict__ cvP, int* __restrict__ jP,
    unsigned* __restrict__ colMaxU, int b0)
{
    __shared__ unsigned colu[1024];          // 4 KB
    const int t = threadIdx.x, wave = t >> 6, lane = t & 63;
    const int blk = blockIdx.x;              // 0 .. CB*1024-1
    const int bbl = blk >> 10;
    const int r10 = blk & 1023;
    const int stripe = r10 >> 2, q = r10 & 3;   // 256 stripes of 16 rows; col quarter
    const int bb = b0 + bbl;
    const int col0 = q * 1024;
    const int row0 = stripe * 16 + wave * 4;

    for (int i = t; i < 1024; i += 256) colu[i] = 0u;
    __syncthreads();

    f32x4 Lc4[4], cmax[4];
    const float* LcB = Lcol + bb * Mm + col0;
#pragma unroll
    for (int c = 0; c < 4; ++c) {
        Lc4[c] = *(const f32x4*)&LcB[c * 256 + lane * 4];
        cmax[c] = (f32x4)(-INFINITY);
    }

    const float* rowbase = simG + (size_t)(bbl * Nn + row0) * Mm + col0;
    f32x4 cur[4], nxt[4];
#pragma unroll
    for (int c = 0; c < 4; ++c)
        cur[c] = __builtin_nontemporal_load((const f32x4*)&rowbase[c * 256 + lane * 4]);

    for (int r = 0; r < 4; ++r) {
        if (r < 3) {
            const float* nrow = rowbase + (size_t)(r + 1) * Mm;
#pragma unroll
            for (int c = 0; c < 4; ++c)
                nxt[c] = __builtin_nontemporal_load((const f32x4*)&nrow[c * 256 + lane * 4]);
        }
        const int n = bb * Nn + row0 + r;
        const float Ln = Lrow[n];
        const float cbias = -40.f - Ln;
        float bk = -INFINITY, bc = -INFINITY;
        int bm = 0x7fffffff;
#pragma unroll
        for (int c = 0; c < 4; ++c) {
            float cv0 = fmaf(40.f, cur[c].x, cbias);
            float cv1 = fmaf(40.f, cur[c].y, cbias);
            float cv2 = fmaf(40.f, cur[c].z, cbias);
            float cv3 = fmaf(40.f, cur[c].w, cbias);
            cmax[c].x = fmaxf(cmax[c].x, cv0);
            cmax[c].y = fmaxf(cmax[c].y, cv1);
            cmax[c].z = fmaxf(cmax[c].z, cv2);
            cmax[c].w = fmaxf(cmax[c].w, cv3);
            const int mb = col0 + c * 256 + lane * 4;
            float kv0 = cv0 - Lc4[c].x;
            float kv1 = cv1 - Lc4[c].y;
            float kv2 = cv2 - Lc4[c].z;
            float kv3 = cv3 - Lc4[c].w;
            if (kv0 > bk) { bk = kv0; bm = mb;     bc = cv0; }
            if (kv1 > bk) { bk = kv1; bm = mb + 1; bc = cv1; }
            if (kv2 > bk) { bk = kv2; bm = mb + 2; bc = cv2; }
            if (kv3 > bk) { bk = kv3; bm = mb + 3; bc = cv3; }
        }
#pragma unroll
        for (int sh = 1; sh < 64; sh <<= 1) {
            float okv = __shfl_xor(bk, sh, 64);
            int   om  = __shfl_xor(bm, sh, 64);
            float ocv = __shfl_xor(bc, sh, 64);
            if (okv > bk || (okv == bk && om < bm)) { bk = okv; bm = om; bc = ocv; }
        }
        if (lane == 0) {
            size_t o = ((size_t)bb * Nn + row0 + r) * 4 + q;
            kvP[o] = bk; cvP[o] = bc; jP[o] = bm;
        }
#pragma unroll
        for (int c = 0; c < 4; ++c) cur[c] = nxt[c];
    }
    // merge the 4 waves' (16 rows') colmax in LDS, then straight to global
#pragma unroll
    for (int c = 0; c < 4; ++c) {
        const int mb = c * 256 + lane * 4;
        atomicMax(&colu[mb],     encf(cmax[c].x));
        atomicMax(&colu[mb + 1], encf(cmax[c].y));
        atomicMax(&colu[mb + 2], encf(cmax[c].z));
        atomicMax(&colu[mb + 3], encf(cmax[c].w));
    }
    __syncthreads();
    unsigned* cm = colMaxU + (size_t)bb * Mm + col0;
    for (int i = t; i < 1024; i += 256) atomicMax(&cm[i], colu[i]);
}

// ---------------- validate rows: merge 4 quarter-candidates, gate ----------------
__global__ __launch_bounds__(256) void validate_kernel(
    const float* __restrict__ kvP, const float* __restrict__ cvP,
    const int* __restrict__ jP, const unsigned* __restrict__ colMaxU,
    float* __restrict__ outJ, int* __restrict__ jIdx, int* __restrict__ v1)
{
    const float LOG_THR = -4.605170185988091f;   // ln(0.01)
    const int p = blockIdx.x * 256 + threadIdx.x;
    const int bb = p >> 12;
    float bk = -INFINITY, bc = -INFINITY;
    int bm = 0x7fffffff;
#pragma unroll
    for (int q = 0; q < 4; ++q) {
        size_t o = (size_t)p * 4 + q;
        float k = kvP[o];
        int   m = jP[o];
        if (k > bk || (k == bk && m < bm)) { bk = k; bm = m; bc = cvP[o]; }
    }
    const float cm = decf(colMaxU[(size_t)bb * Mm + bm]);
    const int ok = (bk > LOG_THR) && (bc >= cm);
    outJ[p] = (float)bm;
    jIdx[p] = bm;
    v1[p] = ok;
}

// ---------------- finalize rows (fallback path) ----------------
__global__ __launch_bounds__(256) void finalize_kernel(
    const float* __restrict__ rkey, const int* __restrict__ rmArr,
    const float* __restrict__ rcvArr, const unsigned* __restrict__ cmU,
    float* __restrict__ outJ, int* __restrict__ jIdx, int* __restrict__ v1)
{
    const float LOG_THR = -4.605170185988091f;
    int p = blockIdx.x * 256 + threadIdx.x;
    int bb = p >> 12, n = p & 4095;
    float bk = -INFINITY, bc = -INFINITY;
    int bm = 0;
    for (int mt = 0; mt < 32; ++mt) {
        size_t idx = (size_t)(bb * 32 + mt) * Nn + n;
        float k = rkey[idx];
        if (k > bk) { bk = k; bm = rmArr[idx]; bc = rcvArr[idx]; }
    }
    unsigned u = 0u;
    for (int nt = 0; nt < 32; ++nt) {
        unsigned c = cmU[(size_t)(bb * 32 + nt) * Mm + bm];
        if (c > u) u = c;
    }
    float cm = decf(u);
    int ok = (bk > LOG_THR) && (bc >= cm);
    outJ[p] = (float)bm;
    jIdx[p] = bm;
    v1[p]   = ok;
}

// ---------------- affine head ----------------
__global__ __launch_bounds__(256) void affine_kernel(
    const float* __restrict__ descA, const float* __restrict__ descB,
    const float* __restrict__ kpA, const float* __restrict__ kpB,
    const float* __restrict__ W, const float* __restrict__ bvec,
    const int* __restrict__ jIdx, const int* __restrict__ v1,
    float* __restrict__ outA, float* __restrict__ outB, float* __restrict__ outV)
{
    __shared__ float Ws[D0c * Kc];
    __shared__ float sbuf[4][4][D0c];
    const int t = threadIdx.x, wave = t >> 6, lane = t & 63;
    for (int i = t; i < D0c * Kc; i += 256) Ws[i] = W[i];
    const float bl = bvec[lane];
    __syncthreads();

    float* s0A = sbuf[wave][0];
    float* s1A = sbuf[wave][1];
    float* s0B = sbuf[wave][2];
    float* s1B = sbuf[wave][3];

    for (int p = 0; p < 8; ++p) {
        const int point = blockIdx.x * 32 + wave * 8 + p;
        const int bb = point >> 12;
        const int j = jIdx[point];
        const float* da = descA + (size_t)point * Dd;
        const float* db = descB + (size_t)(bb * Mm + j) * Dd;
        s0A[lane] = da[lane];       s0A[64 + lane] = da[64 + lane];
        s1A[lane] = da[128 + lane]; s1A[64 + lane] = da[192 + lane];
        s0B[lane] = db[lane];       s0B[64 + lane] = db[64 + lane];
        s1B[lane] = db[128 + lane]; s1B[64 + lane] = db[192 + lane];
        __syncthreads();

        float xa = bl, xb = bl;
#pragma unroll 8
        for (int d = 0; d < 128; ++d) {
            float w_ = Ws[d * 64 + lane];
            xa = fmaf(s0A[d], w_, xa);
            xb = fmaf(s0B[d], w_, xb);
        }
        float wa = softplusf(xa), wb = softplusf(xb);
        float w = sqrtf(wa * wb);
        float x0 = s1A[2 * lane], x1 = s1A[2 * lane + 1];
        float y0 = s1B[2 * lane], y1 = s1B[2 * lane + 1];
        float g00 = w * x0 * x0, g01 = w * x0 * x1, g11 = w * x1 * x1;
        float c00 = w * y0 * x0, c01 = w * y0 * x1;
        float c10 = w * y1 * x0, c11 = w * y1 * x1;
#pragma unroll
        for (int m = 32; m; m >>= 1) {
            g00 += __shfl_xor(g00, m, 64); g01 += __shfl_xor(g01, m, 64); g11 += __shfl_xor(g11, m, 64);
            c00 += __shfl_xor(c00, m, 64); c01 += __shfl_xor(c01, m, 64);
            c10 += __shfl_xor(c10, m, 64); c11 += __shfl_xor(c11, m, 64);
        }
        if (lane == 0) {
            g00 += 1e-6f; g11 += 1e-6f;
            float det = g00 * g11 - g01 * g01;
            float e00 = (c00 * g11 - c01 * g01) / det;
            float e01 = (c01 * g00 - c00 * g01) / det;
            float e10 = (c10 * g11 - c11 * g01) / det;
            float e11 = (c11 * g00 - c10 * g01) / det;
            float m00 = e00 * e00 + e10 * e10;
            float m01 = e00 * e01 + e10 * e11;
            float m11 = e01 * e01 + e11 * e11;
            float tr = m00 + m11;
            float dm = m00 * m11 - m01 * m01;
            float disc = sqrtf(fmaxf(0.25f * tr * tr - dm, 0.f));
            float lhi = 0.5f * tr + disc;
            float llo = fmaxf(0.5f * tr - disc, 0.f);
            float shi = sqrtf(lhi), slo = sqrtf(llo);
            float sdet = e00 * e11 - e01 * e10;
            int good = isfinite(shi + slo) && (shi < 3.0f) && (slo > 0.33333334f) && (sdet > 0.f);
            int valid = v1[point] && good;
            outA[2 * point]     = kpA[2 * point];
            outA[2 * point + 1] = kpA[2 * point + 1];
            const float* kb = kpB + (size_t)(bb * Mm + j) * 2;
            outB[2 * point]     = kb[0];
            outB[2 * point + 1] = kb[1];
            outV[point] = valid ? 1.f : 0.f;
        }
        __syncthreads();
    }
}

extern "C" void kernel_launch(void* const* d_in, const int* in_sizes, int n_in,
                              void* d_out, int out_size, void* d_ws, size_t ws_size,
                              hipStream_t stream) {
    const float* kpA = (const float*)d_in[0];
    const float* dA  = (const float*)d_in[1];
    const float* kpB = (const float*)d_in[2];
    const float* dB  = (const float*)d_in[3];
    const float* W   = (const float*)d_in[4];
    const float* bl  = (const float*)d_in[5];
    float* out = (float*)d_out;

    char* ws = (char*)d_ws;
    _Float16* Ah = (_Float16*)ws;  ws += 8388608;
    _Float16* Al = (_Float16*)ws;  ws += 8388608;
    _Float16* Bh = (_Float16*)ws;  ws += 8388608;
    _Float16* Bl = (_Float16*)ws;  ws += 8388608;
    float*    rowsumP = (float*)ws;    ws += 2097152;
    float*    colsumP = (float*)ws;    ws += 2097152;
    float*    Lrow    = (float*)ws;    ws += 65536;
    float*    Lcol    = (float*)ws;    ws += 65536;
    int*      jIdx    = (int*)ws;      ws += 65536;
    int*      v1      = (int*)ws;      ws += 65536;
    float*    kvP     = (float*)ws;    ws += 262144;
    float*    cvP     = (float*)ws;    ws += 262144;
    int*      jP      = (int*)ws;      ws += 262144;
    unsigned* colMaxU = (unsigned*)ws; ws += 65536;
    char*     big     = ws;

    const size_t base = (size_t)(big - (char*)d_ws);

    // fallback layout (overlays big region)
    float*    rkey  = (float*)big;
    int*      rmArr = (int*)(big + 2097152);
    float*    rcvArr= (float*)(big + 4194304);
    unsigned* cmU   = (unsigned*)(big + 6291456);

    float* outA = out;               // matches_A : 32768
    float* outB = out + 32768;       // matches_B : 32768
    float* outJ = out + 65536;       // j (as f32): 16384
    float* outV = out + 81920;       // valid     : 16384

    const size_t per = 67108864ull;  // CB*64 MB sim matrix
    int CB = 0;
    if      (ws_size >= base + 2 * per) CB = 2;
    else if (ws_size >= base + 1 * per) CB = 1;

    prep_kernel<<<dim3(4096, 2), 256, 0, stream>>>(dA, dB, Ah, Al, Bh, Bl, colMaxU);

    if (CB) {
        float* simG = (float*)big;
        for (int b0 = 0; b0 < Bb; b0 += CB) {
            sim_kernel<0, 1><<<1024 * CB, 256, 0, stream>>>(
                Ah, Al, Bh, Bl, nullptr, nullptr, rowsumP, colsumP,
                nullptr, nullptr, nullptr, nullptr, simG, b0, CB);
            logsum_kernel<<<32 * CB, 256, 0, stream>>>(rowsumP, colsumP, Lrow, Lcol, b0, CB);
            scan_kernel<<<1024 * CB, 256, 0, stream>>>(simG, Lrow, Lcol, kvP, cvP, jP, colMaxU, b0);
        }
        validate_kernel<<<64, 256, 0, stream>>>(kvP, cvP, jP, colMaxU, outJ, jIdx, v1);
    } else {
        sim_kernel<0, 0><<<4096, 256, 0, stream>>>(
            Ah, Al, Bh, Bl, nullptr, nullptr, rowsumP, colsumP,
            nullptr, nullptr, nullptr, nullptr, nullptr, 0, 0);
        logsum_kernel<<<32 * Bb, 256, 0, stream>>>(rowsumP, colsumP, Lrow, Lcol, 0, Bb);
        sim_kernel<1, 0><<<4096, 256, 0, stream>>>(
            Ah, Al, Bh, Bl, Lrow, Lcol, nullptr, nullptr,
            rkey, rmArr, rcvArr, cmU, nullptr, 0, 0);
        finalize_kernel<<<64, 256, 0, stream>>>(rkey, rmArr, rcvArr, cmU, outJ, jIdx, v1);
    }
    affine_kernel<<<512, 256, 0, stream>>>(dA, dB, kpA, kpB, W, bl, jIdx, v1, outA, outB, outV);
}

// Round 11
// 302.336 us; speedup vs baseline: 3.4051x; 1.0528x over previous
//
#include <hip/hip_runtime.h>
#include <math.h>

#define Bb   4
#define Nn   4096
#define Mm   4096
#define Dd   256
#define D0c  128
#define Kc   64

typedef _Float16 half8 __attribute__((ext_vector_type(8)));
typedef float    f32x4 __attribute__((ext_vector_type(4)));

__device__ __forceinline__ unsigned encf(float f) {
    unsigned u = __float_as_uint(f);
    return (u & 0x80000000u) ? ~u : (u | 0x80000000u);
}
__device__ __forceinline__ float decf(unsigned u) {
    return (u & 0x80000000u) ? __uint_as_float(u ^ 0x80000000u) : __uint_as_float(~u);
}
__device__ __forceinline__ float softplusf(float x) {
    return fmaxf(x, 0.f) + log1pf(expf(-fabsf(x)));
}
__device__ __forceinline__ void gl_lds16(const _Float16* g, _Float16* l) {
    __builtin_amdgcn_global_load_lds((const __attribute__((address_space(1))) void*)g,
                                     (__attribute__((address_space(3))) void*)l, 16, 0, 0);
}

// Block->tile decode. swz=2: CB==2 XCD-chunked (2048 blocks; xcd=bid&7 owns one
// 16x16 super-tile of the 32x32 tile grid; panels = 4 MB = one XCD L2).
// swz=1: CB==1. swz=0: plain linear (fallback).
__device__ __forceinline__ void decode_tile(int bid, int swz, int& mt, int& nt, int& zz) {
    if (swz == 2) {
        const int xcd = bid & 7, k = bid >> 3;
        zz = xcd >> 2;
        const int s = xcd & 3;
        mt = (s & 1) * 16 + (k & 15);
        nt = (s >> 1) * 16 + (k >> 4);
    } else if (swz == 1) {
        const int xcd = bid & 7, k = bid >> 3;
        zz = 0;
        const int s = xcd >> 1;
        const int t = (xcd & 1) * 128 + k;
        mt = (s & 1) * 16 + (t & 15);
        nt = (s >> 1) * 16 + (t >> 4);
    } else {
        mt = bid & 31; nt = (bid >> 5) & 31; zz = bid >> 10;
    }
}

// ---------------- prep: normalize rows, split fp16 hi/lo, tiled layout -------------
// lo part stored UNSCALED (x - h) so the correction MFMAs accumulate into the SAME
// fp32 accumulator as h*h (single 64-reg acc -> 3 blocks/CU occupancy).
// also zero-inits the persistent per-batch column-max buffer.
__global__ __launch_bounds__(256) void prep_kernel(
    const float* __restrict__ dA, const float* __restrict__ dB,
    _Float16* __restrict__ Ah, _Float16* __restrict__ Al,
    _Float16* __restrict__ Bh, _Float16* __restrict__ Bl,
    unsigned* __restrict__ colMaxU)
{
    const int t = threadIdx.x, wave = t >> 6, lane = t & 63;
    const int row = blockIdx.x * 4 + wave;           // 0..16383
    if (blockIdx.y == 0 && lane == 0) colMaxU[row] = 0u;
    const float* src = blockIdx.y ? dB : dA;
    _Float16* dh = blockIdx.y ? Bh : Ah;
    _Float16* dl = blockIdx.y ? Bl : Al;
    const float4 v = *(const float4*)&src[(size_t)row * Dd + lane * 4];
    float ss = v.x * v.x + v.y * v.y + v.z * v.z + v.w * v.w;
#pragma unroll
    for (int m = 32; m; m >>= 1) ss += __shfl_xor(ss, m, 64);
    const float inv = 1.0f / sqrtf(ss);
    float x[4] = {v.x * inv, v.y * inv, v.z * inv, v.w * inv};
    union { _Float16 h[4]; uint2 u; } ph, pl;
#pragma unroll
    for (int i = 0; i < 4; i++) {
        _Float16 h = (_Float16)x[i];
        ph.h[i] = h;
        pl.h[i] = (_Float16)(x[i] - (float)h);    // unscaled residual
    }
    const size_t toff = (size_t)(row >> 7) * 32768
                      + (size_t)(lane >> 3) * 4096
                      + (size_t)((lane >> 1) & 3) * 1024
                      + (size_t)(row & 127) * 8 + (lane & 1) * 4;
    *(uint2*)&dh[toff] = ph.u;
    *(uint2*)&dl[toff] = pl.u;
}

// ---------------- MFMA sim kernel ----------------
// Single merged accumulator (h*h + h*l + l*h, lo unscaled), single 32 KB staging
// buffer, __launch_bounds__(256,3) -> 3 blocks/CU so MFMA, LDS and VALU phases of
// different blocks overlap. 2x2 wave quadrants (64x64 per wave). XCD-chunked tile
// decode. STORE path: nontemporal (the 128 MB intermediate streams to HBM).
// Best harness-verified config: 304 us wall, sim 66 us (round 5).
template<int PB, int STORE>
__global__ __launch_bounds__(256, 3) void sim_kernel(
    const _Float16* __restrict__ Ah, const _Float16* __restrict__ Al,
    const _Float16* __restrict__ Bh, const _Float16* __restrict__ Bl,
    const float* __restrict__ Lrow_g, const float* __restrict__ Lcol_g,
    float* __restrict__ rowsumP, float* __restrict__ colsumP,
    float* __restrict__ rkey, int* __restrict__ rmArr, float* __restrict__ rcvArr,
    unsigned* __restrict__ cmU, float* __restrict__ simG, int b0, int swz)
{
    __shared__ _Float16 lds[4][4][128][8];      // 32 KB single-buffer staging
    __shared__ float    colp[128];
    __shared__ float    rowp[128];
    __shared__ unsigned colu[128];
    __shared__ float    shL[128], shLc[128];
    __shared__ float    s_bk[128], s_bc[128];
    __shared__ int      s_bm[128];

    const int t = threadIdx.x;
    const int wave = t >> 6, lane = t & 63;
    const int wr = wave >> 1, wc = wave & 1;    // 2x2 quadrant grid
    int mt, nt, bbl;
    decode_tile(blockIdx.x, swz, mt, nt, bbl);
    const int bb = b0 + bbl;
    const int n0 = nt * 128, m0 = mt * 128;

    if (PB) {
        if (t < 128) {
            shL[t]  = Lrow_g[bb * Nn + n0 + t];
            shLc[t] = Lcol_g[bb * Mm + m0 + t];
            colu[t] = 0u;
        }
    } else {
        if (t < 128) { colp[t] = 0.f; rowp[t] = 0.f; }
    }

    const _Float16* gb;
    {
        const size_t offA = (size_t)(bb * Nn + n0) * Dd;
        const size_t offB = (size_t)(bb * Mm + m0) * Dd;
        if      (wave == 0) gb = Ah + offA;
        else if (wave == 1) gb = Al + offA;
        else if (wave == 2) gb = Bh + offB;
        else                gb = Bl + offB;
    }

    f32x4 acc[4][4];                            // [ti][tj], 64x64 quadrant
#pragma unroll
    for (int ti = 0; ti < 4; ti++)
#pragma unroll
        for (int tj = 0; tj < 4; tj++) acc[ti][tj] = (f32x4)0.f;

    const int quad = lane >> 4, l15 = lane & 15;
    _Float16* ldsw = &lds[wave][0][0][0];

    for (int kc8 = 0; kc8 < 8; ++kc8) {
        const _Float16* gsrc = gb + kc8 * 4096;
#pragma unroll
        for (int q = 0; q < 8; ++q)
            gl_lds16(gsrc + q * 512 + lane * 8, ldsw + q * 512);
        __syncthreads();

        half8 afh[4], afl[4];
#pragma unroll
        for (int ti = 0; ti < 4; ++ti) {
            afh[ti] = *(const half8*)&lds[0][quad][wr * 64 + ti * 16 + l15][0];
            afl[ti] = *(const half8*)&lds[1][quad][wr * 64 + ti * 16 + l15][0];
        }
#pragma unroll
        for (int tj = 0; tj < 4; ++tj) {
            half8 bh = *(const half8*)&lds[2][quad][wc * 64 + tj * 16 + l15][0];
            half8 bl = *(const half8*)&lds[3][quad][wc * 64 + tj * 16 + l15][0];
#pragma unroll
            for (int ti = 0; ti < 4; ++ti) {
                acc[ti][tj] = __builtin_amdgcn_mfma_f32_16x16x32_f16(afh[ti], bh, acc[ti][tj], 0, 0, 0);
                acc[ti][tj] = __builtin_amdgcn_mfma_f32_16x16x32_f16(afh[ti], bl, acc[ti][tj], 0, 0, 0);
                acc[ti][tj] = __builtin_amdgcn_mfma_f32_16x16x32_f16(afl[ti], bh, acc[ti][tj], 0, 0, 0);
            }
        }
        __syncthreads();
    }

    if (!PB) {
        float rp[16], cp[4] = {0.f, 0.f, 0.f, 0.f};
#pragma unroll
        for (int i = 0; i < 16; ++i) rp[i] = 0.f;
#pragma unroll
        for (int ti = 0; ti < 4; ++ti)
#pragma unroll
            for (int tj = 0; tj < 4; ++tj)
#pragma unroll
                for (int r = 0; r < 4; ++r) {
                    float e = __expf(fmaf(20.f, acc[ti][tj][r], -20.f));
                    rp[ti * 4 + r] += e;
                    cp[tj] += e;
                }
#pragma unroll
        for (int i = 0; i < 16; ++i)
#pragma unroll
            for (int m = 1; m < 16; m <<= 1) rp[i] += __shfl_xor(rp[i], m, 64);
        if (l15 == 0) {
#pragma unroll
            for (int ti = 0; ti < 4; ++ti)
#pragma unroll
                for (int r = 0; r < 4; ++r)
                    atomicAdd(&rowp[wr * 64 + ti * 16 + quad * 4 + r], rp[ti * 4 + r]);
        }
#pragma unroll
        for (int tj = 0; tj < 4; ++tj) {
            cp[tj] += __shfl_xor(cp[tj], 16, 64);
            cp[tj] += __shfl_xor(cp[tj], 32, 64);
        }
        if (quad == 0) {
#pragma unroll
            for (int tj = 0; tj < 4; ++tj) atomicAdd(&colp[wc * 64 + tj * 16 + l15], cp[tj]);
        }
        __syncthreads();
        if (t < 128) {
            rowsumP[(size_t)(bb * 32 + mt) * Nn + n0 + t] = rowp[t];
            colsumP[(size_t)(bb * 32 + nt) * Mm + m0 + t] = colp[t];
        }
        if (STORE) {
            // nontemporal: stream to HBM, keep L2 clean for the staged panels
            float* base = simG + ((size_t)bbl * Nn + n0) * Mm + m0 + wc * 64;
#pragma unroll
            for (int ti = 0; ti < 4; ++ti)
#pragma unroll
                for (int r = 0; r < 4; ++r) {
                    float* rowp_ = base + (size_t)(wr * 64 + ti * 16 + quad * 4 + r) * Mm;
#pragma unroll
                    for (int tj = 0; tj < 4; ++tj)
                        __builtin_nontemporal_store(acc[ti][tj][r], rowp_ + tj * 16 + l15);
                }
        }
    } else {
        float Lr[16];
#pragma unroll
        for (int ti = 0; ti < 4; ++ti)
#pragma unroll
            for (int r = 0; r < 4; ++r)
                Lr[ti * 4 + r] = shL[wr * 64 + ti * 16 + quad * 4 + r];

        float bk[16], bc[16];
        int bm[16];
        unsigned cu[4];
#pragma unroll
        for (int i = 0; i < 16; i++) { bk[i] = -INFINITY; bc[i] = -INFINITY; bm[i] = 0x7fffffff; }
#pragma unroll
        for (int j = 0; j < 4; j++) cu[j] = 0u;

#pragma unroll
        for (int ti = 0; ti < 4; ++ti)
#pragma unroll
            for (int tj = 0; tj < 4; ++tj)
#pragma unroll
                for (int r = 0; r < 4; ++r) {
                    float cv = fmaf(40.f, acc[ti][tj][r], -40.f - Lr[ti * 4 + r]);
                    float kv = cv - shLc[wc * 64 + tj * 16 + l15];
                    const int i = ti * 4 + r;
                    if (kv > bk[i]) { bk[i] = kv; bm[i] = m0 + wc * 64 + tj * 16 + l15; bc[i] = cv; }
                    unsigned e = encf(cv);
                    if (e > cu[tj]) cu[tj] = e;
                }
#pragma unroll
        for (int i = 0; i < 16; ++i) {
#pragma unroll
            for (int m = 1; m < 16; m <<= 1) {
                float okv = __shfl_xor(bk[i], m, 64);
                int   om  = __shfl_xor(bm[i], m, 64);
                float ocv = __shfl_xor(bc[i], m, 64);
                if (okv > bk[i] || (okv == bk[i] && om < bm[i])) { bk[i] = okv; bm[i] = om; bc[i] = ocv; }
            }
        }
        // cross-wc merge per row via LDS (two waves cover each row's two halves)
        if (l15 == 0 && wc == 0) {
#pragma unroll
            for (int ti = 0; ti < 4; ++ti)
#pragma unroll
                for (int r = 0; r < 4; ++r) {
                    const int row = wr * 64 + ti * 16 + quad * 4 + r, i = ti * 4 + r;
                    s_bk[row] = bk[i]; s_bm[row] = bm[i]; s_bc[row] = bc[i];
                }
        }
        __syncthreads();
        if (l15 == 0 && wc == 1) {
#pragma unroll
            for (int ti = 0; ti < 4; ++ti)
#pragma unroll
                for (int r = 0; r < 4; ++r) {
                    const int row = wr * 64 + ti * 16 + quad * 4 + r, i = ti * 4 + r;
                    float k0 = s_bk[row];
                    if (bk[i] > k0 || (bk[i] == k0 && bm[i] < s_bm[row])) {
                        s_bk[row] = bk[i]; s_bm[row] = bm[i]; s_bc[row] = bc[i];
                    }
                }
        }
#pragma unroll
        for (int tj = 0; tj < 4; ++tj) {
            unsigned o = __shfl_xor(cu[tj], 16, 64); if (o > cu[tj]) cu[tj] = o;
            o = __shfl_xor(cu[tj], 32, 64); if (o > cu[tj]) cu[tj] = o;
        }
        if (quad == 0) {
#pragma unroll
            for (int tj = 0; tj < 4; ++tj) atomicMax(&colu[wc * 64 + tj * 16 + l15], cu[tj]);
        }
        __syncthreads();
        if (t < 128) {
            size_t idx = (size_t)(bb * 32 + mt) * Nn + n0 + t;
            rkey[idx] = s_bk[t]; rmArr[idx] = s_bm[t]; rcvArr[idx] = s_bc[t];
            cmU[(size_t)(bb * 32 + nt) * Mm + m0 + t] = colu[t];
        }
    }
}

// ---------------- reduce partials -> L = log(rowsum), Lc = log(colsum), chunked -----
__global__ __launch_bounds__(256) void logsum_kernel(
    const float* __restrict__ rowsumP, const float* __restrict__ colsumP,
    float* __restrict__ Lrow, float* __restrict__ Lcol, int b0, int CB)
{
    int t = blockIdx.x * 256 + threadIdx.x;
    int half = CB * 4096;
    int which = t >= half;
    int idx = which ? (t - half) : t;
    int bb = b0 + (idx >> 12), n = idx & 4095;
    const float* P = which ? colsumP : rowsumP;
    float s = 0.f;
    for (int mt = 0; mt < 32; ++mt) s += P[(size_t)(bb * 32 + mt) * 4096 + n];
    (which ? Lcol : Lrow)[bb * 4096 + n] = logf(s);
}

// ---------------- scan: block = 16 rows x 1024 cols (quarter), NT loads ------------
// Column-max goes straight to the persistent per-batch colMaxU via global atomicMax.
__global__ __launch_bounds__(256) void scan_kernel(
    const float* __restrict__ simG,
    const float* __restrict__ Lrow, const float* __restrict__ Lcol,
    float* __restrict__ kvP, float* __restrict__ cvP, int* __restrict__ jP,
    unsigned* __restrict__ colMaxU, int b0)
{
    __shared__ unsigned colu[1024];          // 4 KB
    const int t = threadIdx.x, wave = t >> 6, lane = t & 63;
    const int blk = blockIdx.x;              // 0 .. CB*1024-1
    const int bbl = blk >> 10;
    const int r10 = blk & 1023;
    const int stripe = r10 >> 2, q = r10 & 3;   // 256 stripes of 16 rows; col quarter
    const int bb = b0 + bbl;
    const int col0 = q * 1024;
    const int row0 = stripe * 16 + wave * 4;

    for (int i = t; i < 1024; i += 256) colu[i] = 0u;
    __syncthreads();

    f32x4 Lc4[4], cmax[4];
    const float* LcB = Lcol + bb * Mm + col0;
#pragma unroll
    for (int c = 0; c < 4; ++c) {
        Lc4[c] = *(const f32x4*)&LcB[c * 256 + lane * 4];
        cmax[c] = (f32x4)(-INFINITY);
    }

    const float* rowbase = simG + (size_t)(bbl * Nn + row0) * Mm + col0;
    f32x4 cur[4], nxt[4];
#pragma unroll
    for (int c = 0; c < 4; ++c)
        cur[c] = __builtin_nontemporal_load((const f32x4*)&rowbase[c * 256 + lane * 4]);

    for (int r = 0; r < 4; ++r) {
        if (r < 3) {
            const float* nrow = rowbase + (size_t)(r + 1) * Mm;
#pragma unroll
            for (int c = 0; c < 4; ++c)
                nxt[c] = __builtin_nontemporal_load((const f32x4*)&nrow[c * 256 + lane * 4]);
        }
        const int n = bb * Nn + row0 + r;
        const float Ln = Lrow[n];
        const float cbias = -40.f - Ln;
        float bk = -INFINITY, bc = -INFINITY;
        int bm = 0x7fffffff;
#pragma unroll
        for (int c = 0; c < 4; ++c) {
            float cv0 = fmaf(40.f, cur[c].x, cbias);
            float cv1 = fmaf(40.f, cur[c].y, cbias);
            float cv2 = fmaf(40.f, cur[c].z, cbias);
            float cv3 = fmaf(40.f, cur[c].w, cbias);
            cmax[c].x = fmaxf(cmax[c].x, cv0);
            cmax[c].y = fmaxf(cmax[c].y, cv1);
            cmax[c].z = fmaxf(cmax[c].z, cv2);
            cmax[c].w = fmaxf(cmax[c].w, cv3);
            const int mb = col0 + c * 256 + lane * 4;
            float kv0 = cv0 - Lc4[c].x;
            float kv1 = cv1 - Lc4[c].y;
            float kv2 = cv2 - Lc4[c].z;
            float kv3 = cv3 - Lc4[c].w;
            if (kv0 > bk) { bk = kv0; bm = mb;     bc = cv0; }
            if (kv1 > bk) { bk = kv1; bm = mb + 1; bc = cv1; }
            if (kv2 > bk) { bk = kv2; bm = mb + 2; bc = cv2; }
            if (kv3 > bk) { bk = kv3; bm = mb + 3; bc = cv3; }
        }
#pragma unroll
        for (int sh = 1; sh < 64; sh <<= 1) {
            float okv = __shfl_xor(bk, sh, 64);
            int   om  = __shfl_xor(bm, sh, 64);
            float ocv = __shfl_xor(bc, sh, 64);
            if (okv > bk || (okv == bk && om < bm)) { bk = okv; bm = om; bc = ocv; }
        }
        if (lane == 0) {
            size_t o = ((size_t)bb * Nn + row0 + r) * 4 + q;
            kvP[o] = bk; cvP[o] = bc; jP[o] = bm;
        }
#pragma unroll
        for (int c = 0; c < 4; ++c) cur[c] = nxt[c];
    }
    // merge the 4 waves' (16 rows') colmax in LDS, then straight to global
#pragma unroll
    for (int c = 0; c < 4; ++c) {
        const int mb = c * 256 + lane * 4;
        atomicMax(&colu[mb],     encf(cmax[c].x));
        atomicMax(&colu[mb + 1], encf(cmax[c].y));
        atomicMax(&colu[mb + 2], encf(cmax[c].z));
        atomicMax(&colu[mb + 3], encf(cmax[c].w));
    }
    __syncthreads();
    unsigned* cm = colMaxU + (size_t)bb * Mm + col0;
    for (int i = t; i < 1024; i += 256) atomicMax(&cm[i], colu[i]);
}

// ---------------- validate rows: merge 4 quarter-candidates, gate ----------------
__global__ __launch_bounds__(256) void validate_kernel(
    const float* __restrict__ kvP, const float* __restrict__ cvP,
    const int* __restrict__ jP, const unsigned* __restrict__ colMaxU,
    float* __restrict__ outJ, int* __restrict__ jIdx, int* __restrict__ v1)
{
    const float LOG_THR = -4.605170185988091f;   // ln(0.01)
    const int p = blockIdx.x * 256 + threadIdx.x;
    const int bb = p >> 12;
    float bk = -INFINITY, bc = -INFINITY;
    int bm = 0x7fffffff;
#pragma unroll
    for (int q = 0; q < 4; ++q) {
        size_t o = (size_t)p * 4 + q;
        float k = kvP[o];
        int   m = jP[o];
        if (k > bk || (k == bk && m < bm)) { bk = k; bm = m; bc = cvP[o]; }
    }
    const float cm = decf(colMaxU[(size_t)bb * Mm + bm]);
    const int ok = (bk > LOG_THR) && (bc >= cm);
    outJ[p] = (float)bm;
    jIdx[p] = bm;
    v1[p] = ok;
}

// ---------------- finalize rows (fallback path) ----------------
__global__ __launch_bounds__(256) void finalize_kernel(
    const float* __restrict__ rkey, const int* __restrict__ rmArr,
    const float* __restrict__ rcvArr, const unsigned* __restrict__ cmU,
    float* __restrict__ outJ, int* __restrict__ jIdx, int* __restrict__ v1)
{
    const float LOG_THR = -4.605170185988091f;
    int p = blockIdx.x * 256 + threadIdx.x;
    int bb = p >> 12, n = p & 4095;
    float bk = -INFINITY, bc = -INFINITY;
    int bm = 0;
    for (int mt = 0; mt < 32; ++mt) {
        size_t idx = (size_t)(bb * 32 + mt) * Nn + n;
        float k = rkey[idx];
        if (k > bk) { bk = k; bm = rmArr[idx]; bc = rcvArr[idx]; }
    }
    unsigned u = 0u;
    for (int nt = 0; nt < 32; ++nt) {
        unsigned c = cmU[(size_t)(bb * 32 + nt) * Mm + bm];
        if (c > u) u = c;
    }
    float cm = decf(u);
    int ok = (bk > LOG_THR) && (bc >= cm);
    outJ[p] = (float)bm;
    jIdx[p] = bm;
    v1[p]   = ok;
}

// ---------------- affine head ----------------
__global__ __launch_bounds__(256) void affine_kernel(
    const float* __restrict__ descA, const float* __restrict__ descB,
    const float* __restrict__ kpA, const float* __restrict__ kpB,
    const float* __restrict__ W, const float* __restrict__ bvec,
    const int* __restrict__ jIdx, const int* __restrict__ v1,
    float* __restrict__ outA, float* __restrict__ outB, float* __restrict__ outV)
{
    __shared__ float Ws[D0c * Kc];
    __shared__ float sbuf[4][4][D0c];
    const int t = threadIdx.x, wave = t >> 6, lane = t & 63;
    for (int i = t; i < D0c * Kc; i += 256) Ws[i] = W[i];
    const float bl = bvec[lane];
    __syncthreads();

    float* s0A = sbuf[wave][0];
    float* s1A = sbuf[wave][1];
    float* s0B = sbuf[wave][2];
    float* s1B = sbuf[wave][3];

    for (int p = 0; p < 8; ++p) {
        const int point = blockIdx.x * 32 + wave * 8 + p;
        const int bb = point >> 12;
        const int j = jIdx[point];
        const float* da = descA + (size_t)point * Dd;
        const float* db = descB + (size_t)(bb * Mm + j) * Dd;
        s0A[lane] = da[lane];       s0A[64 + lane] = da[64 + lane];
        s1A[lane] = da[128 + lane]; s1A[64 + lane] = da[192 + lane];
        s0B[lane] = db[lane];       s0B[64 + lane] = db[64 + lane];
        s1B[lane] = db[128 + lane]; s1B[64 + lane] = db[192 + lane];
        __syncthreads();

        float xa = bl, xb = bl;
#pragma unroll 8
        for (int d = 0; d < 128; ++d) {
            float w_ = Ws[d * 64 + lane];
            xa = fmaf(s0A[d], w_, xa);
            xb = fmaf(s0B[d], w_, xb);
        }
        float wa = softplusf(xa), wb = softplusf(xb);
        float w = sqrtf(wa * wb);
        float x0 = s1A[2 * lane], x1 = s1A[2 * lane + 1];
        float y0 = s1B[2 * lane], y1 = s1B[2 * lane + 1];
        float g00 = w * x0 * x0, g01 = w * x0 * x1, g11 = w * x1 * x1;
        float c00 = w * y0 * x0, c01 = w * y0 * x1;
        float c10 = w * y1 * x0, c11 = w * y1 * x1;
#pragma unroll
        for (int m = 32; m; m >>= 1) {
            g00 += __shfl_xor(g00, m, 64); g01 += __shfl_xor(g01, m, 64); g11 += __shfl_xor(g11, m, 64);
            c00 += __shfl_xor(c00, m, 64); c01 += __shfl_xor(c01, m, 64);
            c10 += __shfl_xor(c10, m, 64); c11 += __shfl_xor(c11, m, 64);
        }
        if (lane == 0) {
            g00 += 1e-6f; g11 += 1e-6f;
            float det = g00 * g11 - g01 * g01;
            float e00 = (c00 * g11 - c01 * g01) / det;
            float e01 = (c01 * g00 - c00 * g01) / det;
            float e10 = (c10 * g11 - c11 * g01) / det;
            float e11 = (c11 * g00 - c10 * g01) / det;
            float m00 = e00 * e00 + e10 * e10;
            float m01 = e00 * e01 + e10 * e11;
            float m11 = e01 * e01 + e11 * e11;
            float tr = m00 + m11;
            float dm = m00 * m11 - m01 * m01;
            float disc = sqrtf(fmaxf(0.25f * tr * tr - dm, 0.f));
            float lhi = 0.5f * tr + disc;
            float llo = fmaxf(0.5f * tr - disc, 0.f);
            float shi = sqrtf(lhi), slo = sqrtf(llo);
            float sdet = e00 * e11 - e01 * e10;
            int good = isfinite(shi + slo) && (shi < 3.0f) && (slo > 0.33333334f) && (sdet > 0.f);
            int valid = v1[point] && good;
            outA[2 * point]     = kpA[2 * point];
            outA[2 * point + 1] = kpA[2 * point + 1];
            const float* kb = kpB + (size_t)(bb * Mm + j) * 2;
            outB[2 * point]     = kb[0];
            outB[2 * point + 1] = kb[1];
            outV[point] = valid ? 1.f : 0.f;
        }
        __syncthreads();
    }
}

extern "C" void kernel_launch(void* const* d_in, const int* in_sizes, int n_in,
                              void* d_out, int out_size, void* d_ws, size_t ws_size,
                              hipStream_t stream) {
    const float* kpA = (const float*)d_in[0];
    const float* dA  = (const float*)d_in[1];
    const float* kpB = (const float*)d_in[2];
    const float* dB  = (const float*)d_in[3];
    const float* W   = (const float*)d_in[4];
    const float* bl  = (const float*)d_in[5];
    float* out = (float*)d_out;

    char* ws = (char*)d_ws;
    _Float16* Ah = (_Float16*)ws;  ws += 8388608;
    _Float16* Al = (_Float16*)ws;  ws += 8388608;
    _Float16* Bh = (_Float16*)ws;  ws += 8388608;
    _Float16* Bl = (_Float16*)ws;  ws += 8388608;
    float*    rowsumP = (float*)ws;    ws += 2097152;
    float*    colsumP = (float*)ws;    ws += 2097152;
    float*    Lrow    = (float*)ws;    ws += 65536;
    float*    Lcol    = (float*)ws;    ws += 65536;
    int*      jIdx    = (int*)ws;      ws += 65536;
    int*      v1      = (int*)ws;      ws += 65536;
    float*    kvP     = (float*)ws;    ws += 262144;
    float*    cvP     = (float*)ws;    ws += 262144;
    int*      jP      = (int*)ws;      ws += 262144;
    unsigned* colMaxU = (unsigned*)ws; ws += 65536;
    char*     big     = ws;

    const size_t base = (size_t)(big - (char*)d_ws);

    // fallback layout (overlays big region)
    float*    rkey  = (float*)big;
    int*      rmArr = (int*)(big + 2097152);
    float*    rcvArr= (float*)(big + 4194304);
    unsigned* cmU   = (unsigned*)(big + 6291456);

    float* outA = out;               // matches_A : 32768
    float* outB = out + 32768;       // matches_B : 32768
    float* outJ = out + 65536;       // j (as f32): 16384
    float* outV = out + 81920;       // valid     : 16384

    const size_t per = 67108864ull;  // CB*64 MB sim matrix
    int CB = 0;
    if      (ws_size >= base + 2 * per) CB = 2;
    else if (ws_size >= base + 1 * per) CB = 1;

    prep_kernel<<<dim3(4096, 2), 256, 0, stream>>>(dA, dB, Ah, Al, Bh, Bl, colMaxU);

    if (CB) {
        float* simG = (float*)big;
        for (int b0 = 0; b0 < Bb; b0 += CB) {
            sim_kernel<0, 1><<<1024 * CB, 256, 0, stream>>>(
                Ah, Al, Bh, Bl, nullptr, nullptr, rowsumP, colsumP,
                nullptr, nullptr, nullptr, nullptr, simG, b0, CB);
            logsum_kernel<<<32 * CB, 256, 0, stream>>>(rowsumP, colsumP, Lrow, Lcol, b0, CB);
            scan_kernel<<<1024 * CB, 256, 0, stream>>>(simG, Lrow, Lcol, kvP, cvP, jP, colMaxU, b0);
        }
        validate_kernel<<<64, 256, 0, stream>>>(kvP, cvP, jP, colMaxU, outJ, jIdx, v1);
    } else {
        sim_kernel<0, 0><<<4096, 256, 0, stream>>>(
            Ah, Al, Bh, Bl, nullptr, nullptr, rowsumP, colsumP,
            nullptr, nullptr, nullptr, nullptr, nullptr, 0, 0);
        logsum_kernel<<<32 * Bb, 256, 0, stream>>>(rowsumP, colsumP, Lrow, Lcol, 0, Bb);
        sim_kernel<1, 0><<<4096, 256, 0, stream>>>(
            Ah, Al, Bh, Bl, Lrow, Lcol, nullptr, nullptr,
            rkey, rmArr, rcvArr, cmU, nullptr, 0, 0);
        finalize_kernel<<<64, 256, 0, stream>>>(rkey, rmArr, rcvArr, cmU, outJ, jIdx, v1);
    }
    affine_kernel<<<512, 256, 0, stream>>>(dA, dB, kpA, kpB, W, bl, jIdx, v1, outA, outB, outV);
}